// Round 2
// baseline (88651.685 us; speedup 1.0000x reference)
//
#include <hip/hip_runtime.h>
#include <hip/hip_bf16.h>

#define B_ 2
#define L_ 2048
#define D_ 768
#define H_ 12
#define F_ 3072
#define NL_ 12
#define K_ 128
#define G_ 16
#define HD_ 64
#define CPG_ 48            // D_/G_
#define M_TOK (B_*L_)      // 4096
#define SCALE_ 0.125f      // HD^-0.5
#define QBLK 4

// ---------------------------------------------------------------- transpose
// in (b, R, C) -> out (b, C, R)
__global__ __launch_bounds__(256) void transpose_kernel(const float* __restrict__ in,
                                                        float* __restrict__ out,
                                                        int R, int C) {
  __shared__ float tile[32][33];
  int b = blockIdx.z;
  int r0 = blockIdx.y * 32, c0 = blockIdx.x * 32;
  int tx = threadIdx.x & 31, ty = threadIdx.x >> 5;   // 32 x 8
  const float* ib = in + (size_t)b * R * C;
  float* ob = out + (size_t)b * R * C;
#pragma unroll
  for (int i = 0; i < 32; i += 8)
    tile[ty + i][tx] = ib[(size_t)(r0 + ty + i) * C + (c0 + tx)];
  __syncthreads();
#pragma unroll
  for (int i = 0; i < 32; i += 8)
    ob[(size_t)(c0 + ty + i) * R + (r0 + tx)] = tile[tx][ty + i];
}

// ---------------------------------------------------------------- conv (pos embedding)
// xT (b, d, l) ; w (D, CPG, K); out hT[b][d][l] = xT + gelu(conv + bias)
__global__ __launch_bounds__(256) void conv_kernel(const float* __restrict__ xT,
                                                   const float* __restrict__ w,
                                                   const float* __restrict__ bias,
                                                   float* __restrict__ hT) {
  int idx = blockIdx.x * 256 + threadIdx.x;   // (b, d, l), l fastest
  int l = idx & (L_ - 1);
  int d = (idx >> 11) % D_;                   // idx / L_
  int b = idx / (L_ * D_);
  int g = d / CPG_;
  const float* wd = w + (size_t)d * CPG_ * K_;
  const float* xb = xT + ((size_t)b * D_ + g * CPG_) * L_;
  int klo = max(0, 64 - l);
  int khi = min(K_, L_ + 64 - l);
  float acc = 0.f;
  for (int ci = 0; ci < CPG_; ++ci) {
    const float* xc = xb + (size_t)ci * L_ + (l - 64);
    const float* wk = wd + ci * K_;
    float a2 = 0.f;
    for (int kk = klo; kk < khi; ++kk) a2 += xc[kk] * wk[kk];
    acc += a2;
  }
  float p = acc + bias[d];
  float ge = 0.5f * p * (1.0f + erff(p * 0.70710678118654752f));
  hT[idx] = xT[idx] + ge;
}

// ---------------------------------------------------------------- layernorm (+optional residual add)
// out = LN(a + r) * g + be   (r may be null; out may alias a or r)
__global__ __launch_bounds__(256) void ln_kernel(const float* __restrict__ a,
                                                 const float* __restrict__ r,
                                                 const float* __restrict__ g,
                                                 const float* __restrict__ be,
                                                 float* __restrict__ out) {
  int row = blockIdx.x, tid = threadIdx.x;
  __shared__ float red[256];
  const float* ar = a + (size_t)row * D_;
  float vals[3];
  float s = 0.f;
#pragma unroll
  for (int i = 0; i < 3; ++i) {
    int c = tid + i * 256;
    float vv = ar[c];
    if (r) vv += r[(size_t)row * D_ + c];
    vals[i] = vv; s += vv;
  }
  red[tid] = s; __syncthreads();
  for (int st = 128; st > 0; st >>= 1) {
    if (tid < st) red[tid] += red[tid + st];
    __syncthreads();
  }
  float mean = red[0] * (1.0f / 768.0f);
  __syncthreads();
  float s2 = 0.f;
#pragma unroll
  for (int i = 0; i < 3; ++i) { float d2 = vals[i] - mean; s2 += d2 * d2; }
  red[tid] = s2; __syncthreads();
  for (int st = 128; st > 0; st >>= 1) {
    if (tid < st) red[tid] += red[tid + st];
    __syncthreads();
  }
  float rstd = rsqrtf(red[0] * (1.0f / 768.0f) + 1e-5f);
#pragma unroll
  for (int i = 0; i < 3; ++i) {
    int c = tid + i * 256;
    out[(size_t)row * D_ + c] = (vals[i] - mean) * rstd * g[c] + be[c];
  }
}

// ---------------------------------------------------------------- tiled f32 GEMM
// C[M x N] = A[M x Kd] @ Bm[Kd x N] + bias ;  EPI: 0 = none, 1 = exact gelu
template <int EPI>
__global__ __launch_bounds__(256) void gemm_kernel(const float* __restrict__ A,
                                                   const float* __restrict__ Bm,
                                                   const float* __restrict__ bias,
                                                   float* __restrict__ C,
                                                   int N_, int Kd) {
  const int BM = 128, BN = 64, BK = 16;
  __shared__ float As[BK][BM];
  __shared__ float Bs[BK][BN];
  int bm = blockIdx.y, bn = blockIdx.x;
  int tid = threadIdx.x;
  int tr = tid >> 4, tc = tid & 15;   // 16 x 16
  float acc[8][4] = {};
  const float* Ab = A + (size_t)bm * BM * Kd;
  const float* Bb = Bm + (size_t)bn * BN;
  for (int k0 = 0; k0 < Kd; k0 += BK) {
    {
      int m = tid >> 1;
      int kq = (tid & 1) * 8;
      const float* src = Ab + (size_t)m * Kd + k0 + kq;
      float4 v0 = *(const float4*)(src);
      float4 v1 = *(const float4*)(src + 4);
      As[kq + 0][m] = v0.x; As[kq + 1][m] = v0.y; As[kq + 2][m] = v0.z; As[kq + 3][m] = v0.w;
      As[kq + 4][m] = v1.x; As[kq + 5][m] = v1.y; As[kq + 6][m] = v1.z; As[kq + 7][m] = v1.w;
    }
    {
      int kk = tid >> 4;
      int n = (tid & 15) * 4;
      *(float4*)&Bs[kk][n] = *(const float4*)(Bb + (size_t)(k0 + kk) * N_ + n);
    }
    __syncthreads();
#pragma unroll
    for (int kk = 0; kk < BK; ++kk) {
      float4 a0 = *(const float4*)&As[kk][tr * 8];
      float4 a1 = *(const float4*)&As[kk][tr * 8 + 4];
      float4 b0 = *(const float4*)&Bs[kk][tc * 4];
      float a[8] = {a0.x, a0.y, a0.z, a0.w, a1.x, a1.y, a1.z, a1.w};
      float bb[4] = {b0.x, b0.y, b0.z, b0.w};
#pragma unroll
      for (int i = 0; i < 8; ++i)
#pragma unroll
        for (int j = 0; j < 4; ++j) acc[i][j] += a[i] * bb[j];
    }
    __syncthreads();
  }
  float4 bias4 = *(const float4*)(bias + bn * BN + tc * 4);
#pragma unroll
  for (int i = 0; i < 8; ++i) {
    int m = bm * BM + tr * 8 + i;
    float4 rv;
    rv.x = acc[i][0] + bias4.x;
    rv.y = acc[i][1] + bias4.y;
    rv.z = acc[i][2] + bias4.z;
    rv.w = acc[i][3] + bias4.w;
    if (EPI == 1) {
      rv.x = 0.5f * rv.x * (1.0f + erff(rv.x * 0.70710678f));
      rv.y = 0.5f * rv.y * (1.0f + erff(rv.y * 0.70710678f));
      rv.z = 0.5f * rv.z * (1.0f + erff(rv.z * 0.70710678f));
      rv.w = 0.5f * rv.w * (1.0f + erff(rv.w * 0.70710678f));
    }
    *(float4*)(C + (size_t)m * N_ + bn * BN + tc * 4) = rv;
  }
}

// ---------------------------------------------------------------- attention
// q: (b, l, h, d) ; kT: (b, h, d, m) ; v: (b, m, h, d) ; o: (b, l, h, d)
__global__ __launch_bounds__(256) void attn_kernel(const float* __restrict__ q,
                                                   const float* __restrict__ kT,
                                                   const float* __restrict__ v,
                                                   float* __restrict__ o) {
  int lq0 = blockIdx.x * QBLK;
  int hh = blockIdx.y, b = blockIdx.z;
  int tid = threadIdx.x;
  __shared__ float sc[QBLK][L_];         // 32 KB
  __shared__ float qs[QBLK][HD_];
  __shared__ float red[QBLK][256];
  __shared__ float po[4][QBLK][HD_];

  if (tid < QBLK * HD_) {
    int r = tid >> 6, d = tid & 63;
    qs[r][d] = q[((size_t)(b * L_ + lq0 + r) * D_) + hh * HD_ + d];
  }
  __syncthreads();

  // scores
  float lmax[QBLK] = {-1e30f, -1e30f, -1e30f, -1e30f};
  const float* kbase = kT + (size_t)(b * H_ + hh) * HD_ * L_;
  for (int m = tid; m < L_; m += 256) {
    float s[QBLK] = {0.f, 0.f, 0.f, 0.f};
#pragma unroll
    for (int d0 = 0; d0 < HD_; d0 += 4) {
      float kv0 = kbase[(size_t)(d0 + 0) * L_ + m];
      float kv1 = kbase[(size_t)(d0 + 1) * L_ + m];
      float kv2 = kbase[(size_t)(d0 + 2) * L_ + m];
      float kv3 = kbase[(size_t)(d0 + 3) * L_ + m];
#pragma unroll
      for (int r = 0; r < QBLK; ++r) {
        float4 qv = *(const float4*)&qs[r][d0];
        s[r] += qv.x * kv0 + qv.y * kv1 + qv.z * kv2 + qv.w * kv3;
      }
    }
#pragma unroll
    for (int r = 0; r < QBLK; ++r) {
      float t = s[r] * SCALE_;
      sc[r][m] = t;
      lmax[r] = fmaxf(lmax[r], t);
    }
  }
#pragma unroll
  for (int r = 0; r < QBLK; ++r) red[r][tid] = lmax[r];
  __syncthreads();
  for (int st = 128; st > 0; st >>= 1) {
    if (tid < st)
#pragma unroll
      for (int r = 0; r < QBLK; ++r) red[r][tid] = fmaxf(red[r][tid], red[r][tid + st]);
    __syncthreads();
  }
  float mx[QBLK];
#pragma unroll
  for (int r = 0; r < QBLK; ++r) mx[r] = red[r][0];
  __syncthreads();

  float lsum[QBLK] = {0.f, 0.f, 0.f, 0.f};
  for (int m = tid; m < L_; m += 256) {
#pragma unroll
    for (int r = 0; r < QBLK; ++r) {
      float e = __expf(sc[r][m] - mx[r]);
      sc[r][m] = e;
      lsum[r] += e;
    }
  }
#pragma unroll
  for (int r = 0; r < QBLK; ++r) red[r][tid] = lsum[r];
  __syncthreads();
  for (int st = 128; st > 0; st >>= 1) {
    if (tid < st)
#pragma unroll
      for (int r = 0; r < QBLK; ++r) red[r][tid] += red[r][tid + st];
    __syncthreads();
  }
  float inv[QBLK];
#pragma unroll
  for (int r = 0; r < QBLK; ++r) inv[r] = 1.0f / red[r][0];

  // output
  int grp = tid >> 6, lane = tid & 63;
  float acc[QBLK] = {0.f, 0.f, 0.f, 0.f};
  for (int m = grp; m < L_; m += 4) {
    float vv = v[((size_t)(b * L_ + m) * D_) + hh * HD_ + lane];
#pragma unroll
    for (int r = 0; r < QBLK; ++r) acc[r] += sc[r][m] * vv;
  }
#pragma unroll
  for (int r = 0; r < QBLK; ++r) po[grp][r][lane] = acc[r];
  __syncthreads();
  {
    int r2 = tid >> 6;
    float res = (po[0][r2][lane] + po[1][r2][lane] + po[2][r2][lane] + po[3][r2][lane]) * inv[r2];
    o[((size_t)(b * L_ + lq0 + r2) * D_) + hh * HD_ + lane] = res;
  }
}

// ----------------------------------------------------------------
extern "C" void kernel_launch(void* const* d_in, const int* in_sizes, int n_in,
                              void* d_out, int out_size, void* d_ws, size_t ws_size,
                              hipStream_t stream) {
  const float* x      = (const float*)d_in[0];
  const float* pcw    = (const float*)d_in[1];
  const float* pcb    = (const float*)d_in[2];
  const float* ln0_g  = (const float*)d_in[3];
  const float* ln0_b  = (const float*)d_in[4];
  const float* Wq     = (const float*)d_in[5];
  const float* bq     = (const float*)d_in[6];
  const float* Wk     = (const float*)d_in[7];
  const float* bk     = (const float*)d_in[8];
  const float* Wv     = (const float*)d_in[9];
  const float* bv     = (const float*)d_in[10];
  const float* Wo     = (const float*)d_in[11];
  const float* bo     = (const float*)d_in[12];
  const float* ln1_g  = (const float*)d_in[13];
  const float* ln1_b  = (const float*)d_in[14];
  const float* W1     = (const float*)d_in[15];
  const float* b1     = (const float*)d_in[16];
  const float* W2     = (const float*)d_in[17];
  const float* b2     = (const float*)d_in[18];
  const float* ln2_g  = (const float*)d_in[19];
  const float* ln2_b  = (const float*)d_in[20];

  const size_t MD = (size_t)M_TOK * D_;   // 3,145,728
  float* ws  = (float*)d_ws;
  float* h   = ws;
  float* q   = ws + 1 * MD;
  float* k   = ws + 2 * MD;
  float* kT  = ws + 3 * MD;
  float* v   = ws + 4 * MD;
  float* o   = ws + 5 * MD;
  float* tmp = ws + 6 * MD;
  float* ff  = ws + 1 * MD;               // aliases q..v (dead during FFN); M*F = 4*M*D

  // ---- positional conv embedding + gelu + residual, LN0
  transpose_kernel<<<dim3(D_ / 32, L_ / 32, B_), 256, 0, stream>>>(x, q /*xT*/, L_, D_);
  conv_kernel<<<(B_ * D_ * L_) / 256, 256, 0, stream>>>(q, pcw, pcb, k /*hT*/);
  transpose_kernel<<<dim3(L_ / 32, D_ / 32, B_), 256, 0, stream>>>(k, tmp, D_, L_);
  ln_kernel<<<M_TOK, 256, 0, stream>>>(tmp, nullptr, ln0_g, ln0_b, h);

  dim3 gD(D_ / 64, M_TOK / 128);   // N = 768 GEMMs
  dim3 gF(F_ / 64, M_TOK / 128);   // N = 3072 GEMM
  for (int l = 0; l < NL_; ++l) {
    const float* wq = Wq + (size_t)l * D_ * D_;
    const float* wk = Wk + (size_t)l * D_ * D_;
    const float* wv = Wv + (size_t)l * D_ * D_;
    const float* wo = Wo + (size_t)l * D_ * D_;
    const float* w1 = W1 + (size_t)l * D_ * F_;
    const float* w2 = W2 + (size_t)l * F_ * D_;

    gemm_kernel<0><<<gD, 256, 0, stream>>>(h, wq, bq + (size_t)l * D_, q, D_, D_);
    gemm_kernel<0><<<gD, 256, 0, stream>>>(h, wk, bk + (size_t)l * D_, k, D_, D_);
    gemm_kernel<0><<<gD, 256, 0, stream>>>(h, wv, bv + (size_t)l * D_, v, D_, D_);
    transpose_kernel<<<dim3(D_ / 32, L_ / 32, B_), 256, 0, stream>>>(k, kT, L_, D_);
    attn_kernel<<<dim3(L_ / QBLK, H_, B_), 256, 0, stream>>>(q, kT, v, o);
    gemm_kernel<0><<<gD, 256, 0, stream>>>(o, wo, bo + (size_t)l * D_, tmp, D_, D_);
    ln_kernel<<<M_TOK, 256, 0, stream>>>(tmp, h, ln1_g + (size_t)l * D_, ln1_b + (size_t)l * D_, h);
    gemm_kernel<1><<<gF, 256, 0, stream>>>(h, w1, b1 + (size_t)l * F_, ff, F_, D_);
    gemm_kernel<0><<<gD, 256, 0, stream>>>(ff, w2, b2 + (size_t)l * D_, tmp, D_, F_);
    // last layer's ln2 writes the final f32 output directly
    float* out_ln2 = (l == NL_ - 1) ? (float*)d_out : h;
    ln_kernel<<<M_TOK, 256, 0, stream>>>(tmp, h, ln2_g + (size_t)l * D_, ln2_b + (size_t)l * D_, out_ln2);
  }
}

// Round 4
// 8637.171 us; speedup vs baseline: 10.2640x; 10.2640x over previous
//
#include <hip/hip_runtime.h>
#include <hip/hip_bf16.h>
#include <stdint.h>

#define B_ 2
#define L_ 2048
#define D_ 768
#define H_ 12
#define F_ 3072
#define NL_ 12
#define K_ 128
#define G_ 16
#define HD_ 64
#define CPG_ 48            // D_/G_
#define M_TOK (B_*L_)      // 4096
#define SCALE_ 0.125f      // HD^-0.5

typedef __hip_bfloat16 bf16;
typedef __bf16 bf16x8 __attribute__((ext_vector_type(8)));
typedef float f32x4 __attribute__((ext_vector_type(4)));

__device__ __forceinline__ void gload16(const void* g, void* l) {
  __builtin_amdgcn_global_load_lds((const __attribute__((address_space(1))) void*)g,
                                   (__attribute__((address_space(3))) void*)l, 16, 0, 0);
}

// ---------------------------------------------------------------- f32 transpose (conv prologue)
__global__ __launch_bounds__(256) void transpose_kernel(const float* __restrict__ in,
                                                        float* __restrict__ out,
                                                        int R, int C) {
  __shared__ float tile[32][33];
  int b = blockIdx.z;
  int r0 = blockIdx.y * 32, c0 = blockIdx.x * 32;
  int tx = threadIdx.x & 31, ty = threadIdx.x >> 5;
  const float* ib = in + (size_t)b * R * C;
  float* ob = out + (size_t)b * R * C;
#pragma unroll
  for (int i = 0; i < 32; i += 8)
    tile[ty + i][tx] = ib[(size_t)(r0 + ty + i) * C + (c0 + tx)];
  __syncthreads();
#pragma unroll
  for (int i = 0; i < 32; i += 8)
    ob[(size_t)(c0 + ty + i) * R + (r0 + tx)] = tile[tx][ty + i];
}

// ---------------------------------------------------------------- conv (pos embedding), f32
__global__ __launch_bounds__(256) void conv_kernel(const float* __restrict__ xT,
                                                   const float* __restrict__ w,
                                                   const float* __restrict__ bias,
                                                   float* __restrict__ hT) {
  int idx = blockIdx.x * 256 + threadIdx.x;
  int l = idx & (L_ - 1);
  int d = (idx >> 11) % D_;
  int b = idx / (L_ * D_);
  int g = d / CPG_;
  const float* wd = w + (size_t)d * CPG_ * K_;
  const float* xb = xT + ((size_t)b * D_ + g * CPG_) * L_;
  int klo = max(0, 64 - l);
  int khi = min(K_, L_ + 64 - l);
  float acc = 0.f;
  for (int ci = 0; ci < CPG_; ++ci) {
    const float* xc = xb + (size_t)ci * L_ + (l - 64);
    const float* wk = wd + ci * K_;
    float a2 = 0.f;
    for (int kk = klo; kk < khi; ++kk) a2 += xc[kk] * wk[kk];
    acc += a2;
  }
  float p = acc + bias[d];
  float ge = 0.5f * p * (1.0f + erff(p * 0.70710678118654752f));
  hT[idx] = xT[idx] + ge;
}

// ---------------------------------------------------------------- layernorm (+residual), f32 out + bf16 out
__global__ __launch_bounds__(256) void ln_kernel(const float* __restrict__ a,
                                                 const float* __restrict__ r,
                                                 const float* __restrict__ g,
                                                 const float* __restrict__ be,
                                                 float* __restrict__ out,
                                                 bf16* __restrict__ outb) {
  int row = blockIdx.x, tid = threadIdx.x;
  __shared__ float red[256];
  const float* ar = a + (size_t)row * D_;
  float vals[3];
  float s = 0.f;
#pragma unroll
  for (int i = 0; i < 3; ++i) {
    int c = tid + i * 256;
    float vv = ar[c];
    if (r) vv += r[(size_t)row * D_ + c];
    vals[i] = vv; s += vv;
  }
  red[tid] = s; __syncthreads();
  for (int st = 128; st > 0; st >>= 1) {
    if (tid < st) red[tid] += red[tid + st];
    __syncthreads();
  }
  float mean = red[0] * (1.0f / 768.0f);
  __syncthreads();
  float s2 = 0.f;
#pragma unroll
  for (int i = 0; i < 3; ++i) { float d2 = vals[i] - mean; s2 += d2 * d2; }
  red[tid] = s2; __syncthreads();
  for (int st = 128; st > 0; st >>= 1) {
    if (tid < st) red[tid] += red[tid + st];
    __syncthreads();
  }
  float rstd = rsqrtf(red[0] * (1.0f / 768.0f) + 1e-5f);
#pragma unroll
  for (int i = 0; i < 3; ++i) {
    int c = tid + i * 256;
    float ov = (vals[i] - mean) * rstd * g[c] + be[c];
    out[(size_t)row * D_ + c] = ov;
    if (outb) outb[(size_t)row * D_ + c] = __float2bfloat16(ov);
  }
}

// ---------------------------------------------------------------- transpose-cast f32 [R][C] -> bf16 [C][R]
__global__ __launch_bounds__(256) void castT_kernel(const float* __restrict__ src,
                                                    bf16* __restrict__ dst, int R, int C) {
  __shared__ float t[32][33];
  int c0 = blockIdx.x * 32, r0 = blockIdx.y * 32;
  int tx = threadIdx.x & 31, ty = threadIdx.x >> 5;
#pragma unroll
  for (int i = 0; i < 32; i += 8)
    t[ty + i][tx] = src[(size_t)(r0 + ty + i) * C + (c0 + tx)];
  __syncthreads();
#pragma unroll
  for (int i = 0; i < 32; i += 8)
    dst[(size_t)(c0 + ty + i) * R + (r0 + tx)] = __float2bfloat16(t[tx][ty + i]);
}

// qkv fused: dst[2304][768] from wq/wk/wv [768][768]
__global__ __launch_bounds__(256) void castT_qkv_kernel(const float* __restrict__ q,
                                                        const float* __restrict__ k,
                                                        const float* __restrict__ v,
                                                        bf16* __restrict__ dst) {
  int n0 = blockIdx.x * 32, k0 = blockIdx.y * 32;
  const float* src = (n0 < 768) ? q : (n0 < 1536) ? k : v;
  int nn = (n0 >= 1536) ? (n0 - 1536) : (n0 >= 768 ? n0 - 768 : n0);   // FIX: 768 is not pow2; & 767 was wrong
  __shared__ float t[32][33];
  int tx = threadIdx.x & 31, ty = threadIdx.x >> 5;
#pragma unroll
  for (int i = 0; i < 32; i += 8)
    t[ty + i][tx] = src[(size_t)(k0 + ty + i) * 768 + nn + tx];
  __syncthreads();
#pragma unroll
  for (int i = 0; i < 32; i += 8)
    dst[(size_t)(n0 + ty + i) * 768 + k0 + tx] = __float2bfloat16(t[tx][ty + i]);
}

__global__ __launch_bounds__(256) void bcat_kernel(const float* __restrict__ bq,
                                                   const float* __restrict__ bk,
                                                   const float* __restrict__ bv,
                                                   float* __restrict__ dst) {
  int i = blockIdx.x * 256 + threadIdx.x;
  if (i >= 2304) return;
  dst[i] = (i < 768) ? bq[i] : (i < 1536) ? bk[i - 768] : bv[i - 1536];
}

// v slice of qkv [M][2304] -> vT [(b*12+h)*64 + d][2048]
__global__ __launch_bounds__(256) void vtrans_kernel(const bf16* __restrict__ qkv,
                                                     bf16* __restrict__ vT) {
  int l0 = blockIdx.x * 32, d0 = blockIdx.y * 32, bh = blockIdx.z;
  int b = bh / 12, h = bh % 12;
  __shared__ bf16 t[32][33];
  int tx = threadIdx.x & 31, ty = threadIdx.x >> 5;
#pragma unroll
  for (int i = 0; i < 32; i += 8)
    t[ty + i][tx] = qkv[(size_t)(b * 2048 + l0 + ty + i) * 2304 + 1536 + h * 64 + d0 + tx];
  __syncthreads();
#pragma unroll
  for (int i = 0; i < 32; i += 8)
    vT[((size_t)bh * 64 + d0 + ty + i) * 2048 + l0 + tx] = t[tx][ty + i];
}

// ---------------------------------------------------------------- bf16 MFMA GEMM
// C[M x N] = A[M x Kd] @ BT[N x Kd]^T + bias.  BN=128, BK=64, 4 waves.
template <int BM, int GELU, int BF16OUT>
__global__ __launch_bounds__(256) void gemm_bf16(const bf16* __restrict__ A,
                                                 const bf16* __restrict__ BT,
                                                 const float* __restrict__ bias,
                                                 void* __restrict__ Cout,
                                                 int N, int Kd) {
  constexpr int WM = BM / 2, MF = WM / 16;
  __shared__ bf16 As[BM * 64];
  __shared__ bf16 Bs[128 * 64];
  const int tid = threadIdx.x, w = tid >> 6, lane = tid & 63;
  const int bn = blockIdx.x, bm = blockIdx.y;
  const int wr = w >> 1, wc = w & 1;
  const int c15 = lane & 15, g4 = lane >> 4;
  const int lrow8 = lane >> 3;
  const int cb = (lane & 7) * 16;

  f32x4 acc[MF][4];
  const f32x4 vzero = {0.f, 0.f, 0.f, 0.f};
#pragma unroll
  for (int i = 0; i < MF; ++i)
#pragma unroll
    for (int j = 0; j < 4; ++j) acc[i][j] = vzero;

  const char* Ab = (const char*)A;
  const char* Bb = (const char*)BT;

  for (int k0 = 0; k0 < Kd; k0 += 64) {
    // stage A: BM*128 bytes, pre-swizzled source, linear LDS
#pragma unroll
    for (int i = 0; i < BM / 32; ++i) {
      int t = w + 4 * i;
      int row = t * 8 + lrow8;
      gload16(Ab + ((size_t)(bm * BM + row) * Kd + k0) * 2 + (cb ^ ((row & 7) << 4)),
              (char*)As + t * 1024);
    }
    // stage B: 16 KB
#pragma unroll
    for (int i = 0; i < 4; ++i) {
      int t = w + 4 * i;
      int row = t * 8 + lrow8;
      gload16(Bb + ((size_t)(bn * 128 + row) * Kd + k0) * 2 + (cb ^ ((row & 7) << 4)),
              (char*)Bs + t * 1024);
    }
    __syncthreads();
    bf16x8 af[MF][2], bfr[4][2];
#pragma unroll
    for (int kf = 0; kf < 2; ++kf) {
      int kbyte = kf * 64 + g4 * 16;
#pragma unroll
      for (int mf = 0; mf < MF; ++mf) {
        int row = wr * WM + mf * 16 + c15;
        af[mf][kf] = *(const bf16x8*)((const char*)As + row * 128 + (kbyte ^ ((row & 7) << 4)));
      }
#pragma unroll
      for (int fn = 0; fn < 4; ++fn) {
        int row = wc * 64 + fn * 16 + c15;
        bfr[fn][kf] = *(const bf16x8*)((const char*)Bs + row * 128 + (kbyte ^ ((row & 7) << 4)));
      }
    }
#pragma unroll
    for (int mf = 0; mf < MF; ++mf)
#pragma unroll
      for (int fn = 0; fn < 4; ++fn) {
        acc[mf][fn] = __builtin_amdgcn_mfma_f32_16x16x32_bf16(af[mf][0], bfr[fn][0], acc[mf][fn], 0, 0, 0);
        acc[mf][fn] = __builtin_amdgcn_mfma_f32_16x16x32_bf16(af[mf][1], bfr[fn][1], acc[mf][fn], 0, 0, 0);
      }
    __syncthreads();
  }
  // epilogue
#pragma unroll
  for (int fn = 0; fn < 4; ++fn) {
    int col = bn * 128 + wc * 64 + fn * 16 + c15;
    float bv = bias[col];
#pragma unroll
    for (int mf = 0; mf < MF; ++mf) {
#pragma unroll
      for (int r = 0; r < 4; ++r) {
        int row = bm * BM + wr * WM + mf * 16 + g4 * 4 + r;
        float vv = acc[mf][fn][r] + bv;
        if (GELU) vv = 0.5f * vv * (1.0f + erff(vv * 0.70710678f));
        if (BF16OUT) ((bf16*)Cout)[(size_t)row * N + col] = __float2bfloat16(vv);
        else        ((float*)Cout)[(size_t)row * N + col] = vv;
      }
    }
  }
}

// ---------------------------------------------------------------- flash attention (bf16 MFMA)
// qkv [M][2304] (q|k|v per head h at h*64 / 768+h*64 / 1536+h*64), vT [(b*12+h)*64+d][2048]
__global__ __launch_bounds__(256) void attn_mfma(const bf16* __restrict__ qkv,
                                                 const bf16* __restrict__ vT,
                                                 bf16* __restrict__ ob) {
  const int q0 = blockIdx.x * 64;
  const int h = blockIdx.y, b = blockIdx.z;
  const int tid = threadIdx.x, w = tid >> 6, lane = tid & 63;
  const int c15 = lane & 15, g4 = lane >> 4;
  const int lrow8 = lane >> 3;
  const int cb = (lane & 7) * 16;
  __shared__ bf16 Kl[4096];   // [64 key][64 d], 16B-units swizzled by key&7
  __shared__ bf16 Vl[4096];   // [64 hd][64 key], swizzled by hd&7
  __shared__ bf16 Pl[4096];   // 4 waves x [16 row][64 key], swizzled by row&7

  const f32x4 vzero = {0.f, 0.f, 0.f, 0.f};
  // Q fragments (direct from global)
  const char* qp = (const char*)qkv + (((size_t)(b * 2048 + q0 + w * 16 + c15)) * 2304 + h * 64) * 2;
  bf16x8 qa0 = *(const bf16x8*)(qp + g4 * 16);
  bf16x8 qa1 = *(const bf16x8*)(qp + 64 + g4 * 16);

  f32x4 o[4];
#pragma unroll
  for (int i = 0; i < 4; ++i) o[i] = vzero;
  float m[4] = {-1e30f, -1e30f, -1e30f, -1e30f};
  float lsum[4] = {0.f, 0.f, 0.f, 0.f};

  const char* kgb = (const char*)qkv + (((size_t)(b * 2048)) * 2304 + 768 + h * 64) * 2;
  const char* vgb = (const char*)vT + ((size_t)((b * 12 + h) * 64) * 2048) * 2;
  char* Plw = (char*)Pl + w * 2048;

  for (int kt = 0; kt < 32; ++kt) {
    // stage K and V tiles (8 KB each) with pre-swizzled global source
#pragma unroll
    for (int i = 0; i < 2; ++i) {
      int t = w + 4 * i;
      int rr = t * 8 + lrow8;     // key (K) / hd (V)
      gload16(kgb + (size_t)(kt * 64 + rr) * 4608 + (cb ^ ((rr & 7) << 4)), (char*)Kl + t * 1024);
      gload16(vgb + (size_t)rr * 4096 + (size_t)kt * 128 + (cb ^ ((rr & 7) << 4)), (char*)Vl + t * 1024);
    }
    __syncthreads();
    // S = Q @ K^T  (16 x 64 per wave)
    f32x4 sc[4];
#pragma unroll
    for (int fn = 0; fn < 4; ++fn) {
      int key = fn * 16 + c15;
      const char* kr = (const char*)Kl + key * 128;
      int sw = (key & 7) << 4;
      bf16x8 kb0 = *(const bf16x8*)(kr + ((g4 * 16) ^ sw));
      bf16x8 kb1 = *(const bf16x8*)(kr + ((64 + g4 * 16) ^ sw));
      f32x4 s = __builtin_amdgcn_mfma_f32_16x16x32_bf16(qa0, kb0, vzero, 0, 0, 0);
      s = __builtin_amdgcn_mfma_f32_16x16x32_bf16(qa1, kb1, s, 0, 0, 0);
      sc[fn] = s;
    }
    // online softmax; rows = g4*4 + r
#pragma unroll
    for (int r = 0; r < 4; ++r) {
      float tm = fmaxf(fmaxf(sc[0][r], sc[1][r]), fmaxf(sc[2][r], sc[3][r]));
      tm = fmaxf(tm, __shfl_xor(tm, 1));
      tm = fmaxf(tm, __shfl_xor(tm, 2));
      tm = fmaxf(tm, __shfl_xor(tm, 4));
      tm = fmaxf(tm, __shfl_xor(tm, 8));
      float mn = fmaxf(m[r], tm);
      float alpha = __expf((m[r] - mn) * SCALE_);
      m[r] = mn;
      float rs = 0.f;
#pragma unroll
      for (int fn = 0; fn < 4; ++fn) {
        float p = __expf((sc[fn][r] - mn) * SCALE_);
        sc[fn][r] = p;
        rs += p;
      }
      rs += __shfl_xor(rs, 1);
      rs += __shfl_xor(rs, 2);
      rs += __shfl_xor(rs, 4);
      rs += __shfl_xor(rs, 8);
      lsum[r] = lsum[r] * alpha + rs;
      o[0][r] *= alpha; o[1][r] *= alpha; o[2][r] *= alpha; o[3][r] *= alpha;
      int row = g4 * 4 + r;
      int sw = (row & 7) << 4;
      char* pr = Plw + row * 128;
#pragma unroll
      for (int fn = 0; fn < 4; ++fn) {
        int colb = (fn * 16 + c15) * 2;
        *(bf16*)(pr + (colb ^ sw)) = __float2bfloat16(sc[fn][r]);
      }
    }
    // PV: O += P @ V
    {
      const char* pr = Plw + c15 * 128;
      int sw = (c15 & 7) << 4;
      bf16x8 pa0 = *(const bf16x8*)(pr + ((g4 * 16) ^ sw));
      bf16x8 pa1 = *(const bf16x8*)(pr + ((64 + g4 * 16) ^ sw));
#pragma unroll
      for (int fh = 0; fh < 4; ++fh) {
        int hd = fh * 16 + c15;
        const char* vr = (const char*)Vl + hd * 128;
        int swv = (hd & 7) << 4;
        bf16x8 vb0 = *(const bf16x8*)(vr + ((g4 * 16) ^ swv));
        bf16x8 vb1 = *(const bf16x8*)(vr + ((64 + g4 * 16) ^ swv));
        o[fh] = __builtin_amdgcn_mfma_f32_16x16x32_bf16(pa0, vb0, o[fh], 0, 0, 0);
        o[fh] = __builtin_amdgcn_mfma_f32_16x16x32_bf16(pa1, vb1, o[fh], 0, 0, 0);
      }
    }
    __syncthreads();
  }
  // normalize + write
#pragma unroll
  for (int r = 0; r < 4; ++r) {
    float inv = 1.0f / lsum[r];
    size_t row = (size_t)(b * 2048 + q0 + w * 16 + g4 * 4 + r);
#pragma unroll
    for (int fh = 0; fh < 4; ++fh)
      ob[row * 768 + h * 64 + fh * 16 + c15] = __float2bfloat16(o[fh][r] * inv);
  }
}

// ----------------------------------------------------------------
extern "C" void kernel_launch(void* const* d_in, const int* in_sizes, int n_in,
                              void* d_out, int out_size, void* d_ws, size_t ws_size,
                              hipStream_t stream) {
  const float* x      = (const float*)d_in[0];
  const float* pcw    = (const float*)d_in[1];
  const float* pcb    = (const float*)d_in[2];
  const float* ln0_g  = (const float*)d_in[3];
  const float* ln0_b  = (const float*)d_in[4];
  const float* Wq     = (const float*)d_in[5];
  const float* bq     = (const float*)d_in[6];
  const float* Wk     = (const float*)d_in[7];
  const float* bk     = (const float*)d_in[8];
  const float* Wv     = (const float*)d_in[9];
  const float* bv     = (const float*)d_in[10];
  const float* Wo     = (const float*)d_in[11];
  const float* bo     = (const float*)d_in[12];
  const float* ln1_g  = (const float*)d_in[13];
  const float* ln1_b  = (const float*)d_in[14];
  const float* W1     = (const float*)d_in[15];
  const float* b1     = (const float*)d_in[16];
  const float* W2     = (const float*)d_in[17];
  const float* b2     = (const float*)d_in[18];
  const float* ln2_g  = (const float*)d_in[19];
  const float* ln2_b  = (const float*)d_in[20];

  const size_t MDB = (size_t)M_TOK * D_ * 4;     // 12,582,912 bytes
  char* W = (char*)d_ws;
  float* h    = (float*)W;
  float* tmp  = (float*)(W + MDB);
  char*  big  = W + 2 * MDB;                     // 25,165,824 B region
  bf16*  qkv  = (bf16*)big;                      // [M][2304]
  bf16*  ff   = (bf16*)big;                      // [M][3072] (aliases qkv, disjoint lifetime)
  float* cA   = (float*)big;                     // conv xT
  float* cB   = (float*)(big + MDB);             // conv out
  char* p = W + 2 * MDB + 25165824;
  bf16* h_bf  = (bf16*)p; p += (size_t)M_TOK * D_ * 2;
  bf16* obuf  = (bf16*)p; p += (size_t)M_TOK * D_ * 2;
  bf16* vT    = (bf16*)p; p += (size_t)M_TOK * D_ * 2;
  bf16* wqkvb = (bf16*)p; p += (size_t)2304 * 768 * 2;
  bf16* wob   = (bf16*)p; p += (size_t)768 * 768 * 2;
  bf16* w1b   = (bf16*)p; p += (size_t)3072 * 768 * 2;
  bf16* w2b   = (bf16*)p; p += (size_t)768 * 3072 * 2;
  float* bqkv = (float*)p;

  // ---- conv pos-embedding + gelu + residual, LN0
  transpose_kernel<<<dim3(D_ / 32, L_ / 32, B_), 256, 0, stream>>>(x, cA, L_, D_);
  conv_kernel<<<(B_ * D_ * L_) / 256, 256, 0, stream>>>(cA, pcw, pcb, cB);
  transpose_kernel<<<dim3(L_ / 32, D_ / 32, B_), 256, 0, stream>>>(cB, tmp, D_, L_);
  ln_kernel<<<M_TOK, 256, 0, stream>>>(tmp, nullptr, ln0_g, ln0_b, h, h_bf);

  for (int l = 0; l < NL_; ++l) {
    const float* wq = Wq + (size_t)l * D_ * D_;
    const float* wk = Wk + (size_t)l * D_ * D_;
    const float* wv = Wv + (size_t)l * D_ * D_;
    const float* wo = Wo + (size_t)l * D_ * D_;
    const float* w1 = W1 + (size_t)l * D_ * F_;
    const float* w2 = W2 + (size_t)l * F_ * D_;

    castT_qkv_kernel<<<dim3(72, 24), 256, 0, stream>>>(wq, wk, wv, wqkvb);
    bcat_kernel<<<9, 256, 0, stream>>>(bq + (size_t)l * D_, bk + (size_t)l * D_, bv + (size_t)l * D_, bqkv);
    castT_kernel<<<dim3(24, 24), 256, 0, stream>>>(wo, wob, 768, 768);
    castT_kernel<<<dim3(96, 24), 256, 0, stream>>>(w1, w1b, 768, 3072);
    castT_kernel<<<dim3(24, 96), 256, 0, stream>>>(w2, w2b, 3072, 768);

    // QKV fused GEMM: [M][768] @ [768][2304] -> qkv bf16
    gemm_bf16<128, 0, 1><<<dim3(18, 32), 256, 0, stream>>>(h_bf, wqkvb, bqkv, qkv, 2304, 768);
    vtrans_kernel<<<dim3(64, 2, 24), 256, 0, stream>>>(qkv, vT);
    attn_mfma<<<dim3(32, 12, 2), 256, 0, stream>>>(qkv, vT, obuf);
    // O-proj -> tmp (f32)
    gemm_bf16<64, 0, 0><<<dim3(6, 64), 256, 0, stream>>>(obuf, wob, bo + (size_t)l * D_, tmp, 768, 768);
    ln_kernel<<<M_TOK, 256, 0, stream>>>(tmp, h, ln1_g + (size_t)l * D_, ln1_b + (size_t)l * D_, h, h_bf);
    // FFN
    gemm_bf16<128, 1, 1><<<dim3(24, 32), 256, 0, stream>>>(h_bf, w1b, b1 + (size_t)l * F_, ff, 3072, 768);
    gemm_bf16<64, 0, 0><<<dim3(6, 64), 256, 0, stream>>>(ff, w2b, b2 + (size_t)l * D_, tmp, 768, 3072);
    float* out_ln2 = (l == NL_ - 1) ? (float*)d_out : h;
    ln_kernel<<<M_TOK, 256, 0, stream>>>(tmp, h, ln2_g + (size_t)l * D_, ln2_b + (size_t)l * D_, out_ln2, h_bf);
  }
}

// Round 5
// 3207.317 us; speedup vs baseline: 27.6405x; 2.6930x over previous
//
#include <hip/hip_runtime.h>
#include <hip/hip_bf16.h>
#include <stdint.h>

#define B_ 2
#define L_ 2048
#define D_ 768
#define H_ 12
#define F_ 3072
#define NL_ 12
#define K_ 128
#define G_ 16
#define HD_ 64
#define CPG_ 48            // D_/G_
#define M_TOK (B_*L_)      // 4096
#define SCALE_ 0.125f      // HD^-0.5

typedef __hip_bfloat16 bf16;
typedef __bf16 bf16x8 __attribute__((ext_vector_type(8)));
typedef float f32x4 __attribute__((ext_vector_type(4)));

__device__ __forceinline__ void gload16(const void* g, void* l) {
  __builtin_amdgcn_global_load_lds((const __attribute__((address_space(1))) void*)g,
                                   (__attribute__((address_space(3))) void*)l, 16, 0, 0);
}

// ---------------------------------------------------------------- conv weight pre-transpose
// pcw f32 [768][48][128] (d_global, ci, kk) -> wT2 bf16 [g][kk][d(48)][ci(64, zero-pad 48..63)]
__global__ __launch_bounds__(256) void convw_kernel(const float* __restrict__ w,
                                                    bf16* __restrict__ wT2) {
  int idx = blockIdx.x * 256 + threadIdx.x;        // 16*128*48*64 = 6,291,456
  int ci = idx & 63;
  int row = idx >> 6;                              // (g*128+kk)*48 + d
  int d = row % 48;
  int t2 = row / 48;
  int kk = t2 & 127;
  int g = t2 >> 7;
  float v = (ci < 48) ? w[(((size_t)(g * 48 + d) * 48) + ci) * 128 + kk] : 0.f;
  wT2[idx] = __float2bfloat16(v);
}

// ---------------------------------------------------------------- conv via MFMA
// x f32 [b][l][768]; wT2 as above; out[b][l][768] = x + gelu(conv + bias)
__global__ __launch_bounds__(256) void conv_mfma(const float* __restrict__ x,
                                                 const bf16* __restrict__ wT2,
                                                 const float* __restrict__ bias,
                                                 float* __restrict__ out) {
  const int l0 = blockIdx.x * 64, g = blockIdx.y, b = blockIdx.z;
  const int tid = threadIdx.x, w = tid >> 6, lane = tid & 63;
  const int c15 = lane & 15, g4 = lane >> 4;
  __shared__ __align__(16) bf16 win[192 * 72];   // [pos][72]: ci 0..47 data, bytes 96..127 zeroed
  __shared__ __align__(16) bf16 Wl[2 * 48 * 64]; // two kk slices, 128B rows, swizzled content

  // ---- stage x window (f32 -> bf16); zero OOB rows and pad cols
  if (tid < 192) {
    int lg = l0 - 64 + tid;
    char* dst = (char*)win + tid * 144;
    uint4 z4 = {0u, 0u, 0u, 0u};
    if ((unsigned)lg < 2048u) {
      const float* srow = x + ((size_t)(b * 2048 + lg) * 768 + g * 48);
#pragma unroll
      for (int c = 0; c < 6; ++c) {
        float4 v0 = *(const float4*)(srow + c * 8);
        float4 v1 = *(const float4*)(srow + c * 8 + 4);
        union { bf16 h[8]; uint4 u; } uu;
        uu.h[0] = __float2bfloat16(v0.x); uu.h[1] = __float2bfloat16(v0.y);
        uu.h[2] = __float2bfloat16(v0.z); uu.h[3] = __float2bfloat16(v0.w);
        uu.h[4] = __float2bfloat16(v1.x); uu.h[5] = __float2bfloat16(v1.y);
        uu.h[6] = __float2bfloat16(v1.z); uu.h[7] = __float2bfloat16(v1.w);
        *(uint4*)(dst + c * 16) = uu.u;
      }
    } else {
#pragma unroll
      for (int c = 0; c < 6; ++c) *(uint4*)(dst + c * 16) = z4;
    }
    *(uint4*)(dst + 96) = z4;      // zero ci 48..55
    *(uint4*)(dst + 112) = z4;     // zero ci 56..63
  }
  __syncthreads();

  f32x4 acc[3];
  const f32x4 vzero = {0.f, 0.f, 0.f, 0.f};
  acc[0] = vzero; acc[1] = vzero; acc[2] = vzero;

  const char* wbase = (const char*)wT2 + (size_t)g * 128 * 48 * 128;  // g-slice

  for (int kp = 0; kp < 64; ++kp) {
    // stage two kk-slices (12288 B); wave w covers [w*3072, w*3072+3072)
#pragma unroll
    for (int i = 0; i < 3; ++i) {
      int coff = w * 3072 + i * 1024;           // wave-uniform LDS base
      int c = coff + (lane << 4);               // this lane's dest byte
      int row96 = c >> 7;                       // 0..95
      int s = row96 / 48;
      int d = row96 - s * 48;
      int cb = c & 127;
      gload16(wbase + ((size_t)((2 * kp + s) * 48 + d)) * 128 + (cb ^ ((d & 7) << 4)),
              (char*)Wl + coff);
    }
    __syncthreads();
#pragma unroll
    for (int s = 0; s < 2; ++s) {
      int kk = 2 * kp + s;
#pragma unroll
      for (int cb = 0; cb < 2; ++cb) {
        bf16x8 a = *(const bf16x8*)((const char*)win + (w * 16 + c15 + kk) * 144 + cb * 64 + g4 * 16);
#pragma unroll
        for (int ct = 0; ct < 3; ++ct) {
          int d = ct * 16 + c15;
          bf16x8 bfrag = *(const bf16x8*)((const char*)Wl + s * 6144 + d * 128 +
                                          ((cb * 64 + g4 * 16) ^ ((d & 7) << 4)));
          acc[ct] = __builtin_amdgcn_mfma_f32_16x16x32_bf16(a, bfrag, acc[ct], 0, 0, 0);
        }
      }
    }
    __syncthreads();
  }

  // epilogue: bias + exact gelu + residual, natural layout
#pragma unroll
  for (int ct = 0; ct < 3; ++ct) {
    int dg = g * 48 + ct * 16 + c15;
    float bv = bias[dg];
#pragma unroll
    for (int r = 0; r < 4; ++r) {
      int l = l0 + w * 16 + g4 * 4 + r;
      size_t idx = (size_t)(b * 2048 + l) * 768 + dg;
      float vv = acc[ct][r] + bv;
      vv = 0.5f * vv * (1.0f + erff(vv * 0.70710678f));
      out[idx] = x[idx] + vv;
    }
  }
}

// ---------------------------------------------------------------- layernorm (+residual), f32 out + bf16 out
__global__ __launch_bounds__(256) void ln_kernel(const float* __restrict__ a,
                                                 const float* __restrict__ r,
                                                 const float* __restrict__ g,
                                                 const float* __restrict__ be,
                                                 float* __restrict__ out,
                                                 bf16* __restrict__ outb) {
  int row = blockIdx.x, tid = threadIdx.x;
  __shared__ float red[256];
  const float* ar = a + (size_t)row * D_;
  float vals[3];
  float s = 0.f;
#pragma unroll
  for (int i = 0; i < 3; ++i) {
    int c = tid + i * 256;
    float vv = ar[c];
    if (r) vv += r[(size_t)row * D_ + c];
    vals[i] = vv; s += vv;
  }
  red[tid] = s; __syncthreads();
  for (int st = 128; st > 0; st >>= 1) {
    if (tid < st) red[tid] += red[tid + st];
    __syncthreads();
  }
  float mean = red[0] * (1.0f / 768.0f);
  __syncthreads();
  float s2 = 0.f;
#pragma unroll
  for (int i = 0; i < 3; ++i) { float d2 = vals[i] - mean; s2 += d2 * d2; }
  red[tid] = s2; __syncthreads();
  for (int st = 128; st > 0; st >>= 1) {
    if (tid < st) red[tid] += red[tid + st];
    __syncthreads();
  }
  float rstd = rsqrtf(red[0] * (1.0f / 768.0f) + 1e-5f);
#pragma unroll
  for (int i = 0; i < 3; ++i) {
    int c = tid + i * 256;
    float ov = (vals[i] - mean) * rstd * g[c] + be[c];
    out[(size_t)row * D_ + c] = ov;
    if (outb) outb[(size_t)row * D_ + c] = __float2bfloat16(ov);
  }
}

// ---------------------------------------------------------------- transpose-cast f32 [R][C] -> bf16 [C][R]
__global__ __launch_bounds__(256) void castT_kernel(const float* __restrict__ src,
                                                    bf16* __restrict__ dst, int R, int C) {
  __shared__ float t[32][33];
  int c0 = blockIdx.x * 32, r0 = blockIdx.y * 32;
  int tx = threadIdx.x & 31, ty = threadIdx.x >> 5;
#pragma unroll
  for (int i = 0; i < 32; i += 8)
    t[ty + i][tx] = src[(size_t)(r0 + ty + i) * C + (c0 + tx)];
  __syncthreads();
#pragma unroll
  for (int i = 0; i < 32; i += 8)
    dst[(size_t)(c0 + ty + i) * R + (r0 + tx)] = __float2bfloat16(t[tx][ty + i]);
}

// qkv fused: dst[2304][768] from wq/wk/wv [768][768]
__global__ __launch_bounds__(256) void castT_qkv_kernel(const float* __restrict__ q,
                                                        const float* __restrict__ k,
                                                        const float* __restrict__ v,
                                                        bf16* __restrict__ dst) {
  int n0 = blockIdx.x * 32, k0 = blockIdx.y * 32;
  const float* src = (n0 < 768) ? q : (n0 < 1536) ? k : v;
  int nn = (n0 >= 1536) ? (n0 - 1536) : (n0 >= 768 ? n0 - 768 : n0);   // 768 is not pow2
  __shared__ float t[32][33];
  int tx = threadIdx.x & 31, ty = threadIdx.x >> 5;
#pragma unroll
  for (int i = 0; i < 32; i += 8)
    t[ty + i][tx] = src[(size_t)(k0 + ty + i) * 768 + nn + tx];
  __syncthreads();
#pragma unroll
  for (int i = 0; i < 32; i += 8)
    dst[(size_t)(n0 + ty + i) * 768 + k0 + tx] = __float2bfloat16(t[tx][ty + i]);
}

__global__ __launch_bounds__(256) void bcat_kernel(const float* __restrict__ bq,
                                                   const float* __restrict__ bk,
                                                   const float* __restrict__ bv,
                                                   float* __restrict__ dst) {
  int i = blockIdx.x * 256 + threadIdx.x;
  if (i >= 2304) return;
  dst[i] = (i < 768) ? bq[i] : (i < 1536) ? bk[i - 768] : bv[i - 1536];
}

// v slice of qkv [M][2304] -> vT [(b*12+h)*64 + d][2048]
__global__ __launch_bounds__(256) void vtrans_kernel(const bf16* __restrict__ qkv,
                                                     bf16* __restrict__ vT) {
  int l0 = blockIdx.x * 32, d0 = blockIdx.y * 32, bh = blockIdx.z;
  int b = bh / 12, h = bh % 12;
  __shared__ bf16 t[32][33];
  int tx = threadIdx.x & 31, ty = threadIdx.x >> 5;
#pragma unroll
  for (int i = 0; i < 32; i += 8)
    t[ty + i][tx] = qkv[(size_t)(b * 2048 + l0 + ty + i) * 2304 + 1536 + h * 64 + d0 + tx];
  __syncthreads();
#pragma unroll
  for (int i = 0; i < 32; i += 8)
    vT[((size_t)bh * 64 + d0 + ty + i) * 2048 + l0 + tx] = t[tx][ty + i];
}

// ---------------------------------------------------------------- bf16 MFMA GEMM
// C[M x N] = A[M x Kd] @ BT[N x Kd]^T + bias.  BN=128, BK=64, 4 waves.
template <int BM, int GELU, int BF16OUT>
__global__ __launch_bounds__(256) void gemm_bf16(const bf16* __restrict__ A,
                                                 const bf16* __restrict__ BT,
                                                 const float* __restrict__ bias,
                                                 void* __restrict__ Cout,
                                                 int N, int Kd) {
  constexpr int WM = BM / 2, MF = WM / 16;
  __shared__ bf16 As[BM * 64];
  __shared__ bf16 Bs[128 * 64];
  const int tid = threadIdx.x, w = tid >> 6, lane = tid & 63;
  const int bn = blockIdx.x, bm = blockIdx.y;
  const int wr = w >> 1, wc = w & 1;
  const int c15 = lane & 15, g4 = lane >> 4;
  const int lrow8 = lane >> 3;
  const int cb = (lane & 7) * 16;

  f32x4 acc[MF][4];
  const f32x4 vzero = {0.f, 0.f, 0.f, 0.f};
#pragma unroll
  for (int i = 0; i < MF; ++i)
#pragma unroll
    for (int j = 0; j < 4; ++j) acc[i][j] = vzero;

  const char* Ab = (const char*)A;
  const char* Bb = (const char*)BT;

  for (int k0 = 0; k0 < Kd; k0 += 64) {
#pragma unroll
    for (int i = 0; i < BM / 32; ++i) {
      int t = w + 4 * i;
      int row = t * 8 + lrow8;
      gload16(Ab + ((size_t)(bm * BM + row) * Kd + k0) * 2 + (cb ^ ((row & 7) << 4)),
              (char*)As + t * 1024);
    }
#pragma unroll
    for (int i = 0; i < 4; ++i) {
      int t = w + 4 * i;
      int row = t * 8 + lrow8;
      gload16(Bb + ((size_t)(bn * 128 + row) * Kd + k0) * 2 + (cb ^ ((row & 7) << 4)),
              (char*)Bs + t * 1024);
    }
    __syncthreads();
    bf16x8 af[MF][2], bfr[4][2];
#pragma unroll
    for (int kf = 0; kf < 2; ++kf) {
      int kbyte = kf * 64 + g4 * 16;
#pragma unroll
      for (int mf = 0; mf < MF; ++mf) {
        int row = wr * WM + mf * 16 + c15;
        af[mf][kf] = *(const bf16x8*)((const char*)As + row * 128 + (kbyte ^ ((row & 7) << 4)));
      }
#pragma unroll
      for (int fn = 0; fn < 4; ++fn) {
        int row = wc * 64 + fn * 16 + c15;
        bfr[fn][kf] = *(const bf16x8*)((const char*)Bs + row * 128 + (kbyte ^ ((row & 7) << 4)));
      }
    }
#pragma unroll
    for (int mf = 0; mf < MF; ++mf)
#pragma unroll
      for (int fn = 0; fn < 4; ++fn) {
        acc[mf][fn] = __builtin_amdgcn_mfma_f32_16x16x32_bf16(af[mf][0], bfr[fn][0], acc[mf][fn], 0, 0, 0);
        acc[mf][fn] = __builtin_amdgcn_mfma_f32_16x16x32_bf16(af[mf][1], bfr[fn][1], acc[mf][fn], 0, 0, 0);
      }
    __syncthreads();
  }
#pragma unroll
  for (int fn = 0; fn < 4; ++fn) {
    int col = bn * 128 + wc * 64 + fn * 16 + c15;
    float bv = bias[col];
#pragma unroll
    for (int mf = 0; mf < MF; ++mf) {
#pragma unroll
      for (int r = 0; r < 4; ++r) {
        int row = bm * BM + wr * WM + mf * 16 + g4 * 4 + r;
        float vv = acc[mf][fn][r] + bv;
        if (GELU) vv = 0.5f * vv * (1.0f + erff(vv * 0.70710678f));
        if (BF16OUT) ((bf16*)Cout)[(size_t)row * N + col] = __float2bfloat16(vv);
        else        ((float*)Cout)[(size_t)row * N + col] = vv;
      }
    }
  }
}

// ---------------------------------------------------------------- flash attention (bf16 MFMA)
__global__ __launch_bounds__(256) void attn_mfma(const bf16* __restrict__ qkv,
                                                 const bf16* __restrict__ vT,
                                                 bf16* __restrict__ ob) {
  const int q0 = blockIdx.x * 64;
  const int h = blockIdx.y, b = blockIdx.z;
  const int tid = threadIdx.x, w = tid >> 6, lane = tid & 63;
  const int c15 = lane & 15, g4 = lane >> 4;
  const int lrow8 = lane >> 3;
  const int cb = (lane & 7) * 16;
  __shared__ bf16 Kl[4096];
  __shared__ bf16 Vl[4096];
  __shared__ bf16 Pl[4096];

  const f32x4 vzero = {0.f, 0.f, 0.f, 0.f};
  const char* qp = (const char*)qkv + (((size_t)(b * 2048 + q0 + w * 16 + c15)) * 2304 + h * 64) * 2;
  bf16x8 qa0 = *(const bf16x8*)(qp + g4 * 16);
  bf16x8 qa1 = *(const bf16x8*)(qp + 64 + g4 * 16);

  f32x4 o[4];
#pragma unroll
  for (int i = 0; i < 4; ++i) o[i] = vzero;
  float m[4] = {-1e30f, -1e30f, -1e30f, -1e30f};
  float lsum[4] = {0.f, 0.f, 0.f, 0.f};

  const char* kgb = (const char*)qkv + (((size_t)(b * 2048)) * 2304 + 768 + h * 64) * 2;
  const char* vgb = (const char*)vT + ((size_t)((b * 12 + h) * 64) * 2048) * 2;
  char* Plw = (char*)Pl + w * 2048;

  for (int kt = 0; kt < 32; ++kt) {
#pragma unroll
    for (int i = 0; i < 2; ++i) {
      int t = w + 4 * i;
      int rr = t * 8 + lrow8;
      gload16(kgb + (size_t)(kt * 64 + rr) * 4608 + (cb ^ ((rr & 7) << 4)), (char*)Kl + t * 1024);
      gload16(vgb + (size_t)rr * 4096 + (size_t)kt * 128 + (cb ^ ((rr & 7) << 4)), (char*)Vl + t * 1024);
    }
    __syncthreads();
    f32x4 sc[4];
#pragma unroll
    for (int fn = 0; fn < 4; ++fn) {
      int key = fn * 16 + c15;
      const char* kr = (const char*)Kl + key * 128;
      int sw = (key & 7) << 4;
      bf16x8 kb0 = *(const bf16x8*)(kr + ((g4 * 16) ^ sw));
      bf16x8 kb1 = *(const bf16x8*)(kr + ((64 + g4 * 16) ^ sw));
      f32x4 s = __builtin_amdgcn_mfma_f32_16x16x32_bf16(qa0, kb0, vzero, 0, 0, 0);
      s = __builtin_amdgcn_mfma_f32_16x16x32_bf16(qa1, kb1, s, 0, 0, 0);
      sc[fn] = s;
    }
#pragma unroll
    for (int r = 0; r < 4; ++r) {
      float tm = fmaxf(fmaxf(sc[0][r], sc[1][r]), fmaxf(sc[2][r], sc[3][r]));
      tm = fmaxf(tm, __shfl_xor(tm, 1));
      tm = fmaxf(tm, __shfl_xor(tm, 2));
      tm = fmaxf(tm, __shfl_xor(tm, 4));
      tm = fmaxf(tm, __shfl_xor(tm, 8));
      float mn = fmaxf(m[r], tm);
      float alpha = __expf((m[r] - mn) * SCALE_);
      m[r] = mn;
      float rs = 0.f;
#pragma unroll
      for (int fn = 0; fn < 4; ++fn) {
        float p = __expf((sc[fn][r] - mn) * SCALE_);
        sc[fn][r] = p;
        rs += p;
      }
      rs += __shfl_xor(rs, 1);
      rs += __shfl_xor(rs, 2);
      rs += __shfl_xor(rs, 4);
      rs += __shfl_xor(rs, 8);
      lsum[r] = lsum[r] * alpha + rs;
      o[0][r] *= alpha; o[1][r] *= alpha; o[2][r] *= alpha; o[3][r] *= alpha;
      int row = g4 * 4 + r;
      int sw = (row & 7) << 4;
      char* pr = Plw + row * 128;
#pragma unroll
      for (int fn = 0; fn < 4; ++fn) {
        int colb = (fn * 16 + c15) * 2;
        *(bf16*)(pr + (colb ^ sw)) = __float2bfloat16(sc[fn][r]);
      }
    }
    {
      const char* pr = Plw + c15 * 128;
      int sw = (c15 & 7) << 4;
      bf16x8 pa0 = *(const bf16x8*)(pr + ((g4 * 16) ^ sw));
      bf16x8 pa1 = *(const bf16x8*)(pr + ((64 + g4 * 16) ^ sw));
#pragma unroll
      for (int fh = 0; fh < 4; ++fh) {
        int hd = fh * 16 + c15;
        const char* vr = (const char*)Vl + hd * 128;
        int swv = (hd & 7) << 4;
        bf16x8 vb0 = *(const bf16x8*)(vr + ((g4 * 16) ^ swv));
        bf16x8 vb1 = *(const bf16x8*)(vr + ((64 + g4 * 16) ^ swv));
        o[fh] = __builtin_amdgcn_mfma_f32_16x16x32_bf16(pa0, vb0, o[fh], 0, 0, 0);
        o[fh] = __builtin_amdgcn_mfma_f32_16x16x32_bf16(pa1, vb1, o[fh], 0, 0, 0);
      }
    }
    __syncthreads();
  }
#pragma unroll
  for (int r = 0; r < 4; ++r) {
    float inv = 1.0f / lsum[r];
    size_t row = (size_t)(b * 2048 + q0 + w * 16 + g4 * 4 + r);
#pragma unroll
    for (int fh = 0; fh < 4; ++fh)
      ob[row * 768 + h * 64 + fh * 16 + c15] = __float2bfloat16(o[fh][r] * inv);
  }
}

// ----------------------------------------------------------------
extern "C" void kernel_launch(void* const* d_in, const int* in_sizes, int n_in,
                              void* d_out, int out_size, void* d_ws, size_t ws_size,
                              hipStream_t stream) {
  const float* x      = (const float*)d_in[0];
  const float* pcw    = (const float*)d_in[1];
  const float* pcb    = (const float*)d_in[2];
  const float* ln0_g  = (const float*)d_in[3];
  const float* ln0_b  = (const float*)d_in[4];
  const float* Wq     = (const float*)d_in[5];
  const float* bq     = (const float*)d_in[6];
  const float* Wk     = (const float*)d_in[7];
  const float* bk     = (const float*)d_in[8];
  const float* Wv     = (const float*)d_in[9];
  const float* bv     = (const float*)d_in[10];
  const float* Wo     = (const float*)d_in[11];
  const float* bo     = (const float*)d_in[12];
  const float* ln1_g  = (const float*)d_in[13];
  const float* ln1_b  = (const float*)d_in[14];
  const float* W1     = (const float*)d_in[15];
  const float* b1     = (const float*)d_in[16];
  const float* W2     = (const float*)d_in[17];
  const float* b2     = (const float*)d_in[18];
  const float* ln2_g  = (const float*)d_in[19];
  const float* ln2_b  = (const float*)d_in[20];

  const size_t MDB = (size_t)M_TOK * D_ * 4;     // 12,582,912 bytes
  char* W = (char*)d_ws;
  float* h    = (float*)W;
  float* tmp  = (float*)(W + MDB);
  char*  big  = W + 2 * MDB;                     // 25,165,824 B region
  bf16*  qkv  = (bf16*)big;                      // [M][2304]
  bf16*  ff   = (bf16*)big;                      // [M][3072] (aliases qkv)
  bf16*  wT2  = (bf16*)big;                      // conv weights (dead before qkv lives)
  char* p = W + 2 * MDB + 25165824;
  bf16* h_bf  = (bf16*)p; p += (size_t)M_TOK * D_ * 2;
  bf16* obuf  = (bf16*)p; p += (size_t)M_TOK * D_ * 2;
  bf16* vT    = (bf16*)p; p += (size_t)M_TOK * D_ * 2;
  bf16* wqkvb = (bf16*)p; p += (size_t)2304 * 768 * 2;
  bf16* wob   = (bf16*)p; p += (size_t)768 * 768 * 2;
  bf16* w1b   = (bf16*)p; p += (size_t)3072 * 768 * 2;
  bf16* w2b   = (bf16*)p; p += (size_t)768 * 3072 * 2;
  float* bqkv = (float*)p;

  // ---- conv pos-embedding via MFMA + gelu + residual, LN0
  convw_kernel<<<24576, 256, 0, stream>>>(pcw, wT2);
  conv_mfma<<<dim3(32, 16, 2), 256, 0, stream>>>(x, wT2, pcb, tmp);
  ln_kernel<<<M_TOK, 256, 0, stream>>>(tmp, nullptr, ln0_g, ln0_b, h, h_bf);

  for (int l = 0; l < NL_; ++l) {
    const float* wq = Wq + (size_t)l * D_ * D_;
    const float* wk = Wk + (size_t)l * D_ * D_;
    const float* wv = Wv + (size_t)l * D_ * D_;
    const float* wo = Wo + (size_t)l * D_ * D_;
    const float* w1 = W1 + (size_t)l * D_ * F_;
    const float* w2 = W2 + (size_t)l * F_ * D_;

    castT_qkv_kernel<<<dim3(72, 24), 256, 0, stream>>>(wq, wk, wv, wqkvb);
    bcat_kernel<<<9, 256, 0, stream>>>(bq + (size_t)l * D_, bk + (size_t)l * D_, bv + (size_t)l * D_, bqkv);
    castT_kernel<<<dim3(24, 24), 256, 0, stream>>>(wo, wob, 768, 768);
    castT_kernel<<<dim3(96, 24), 256, 0, stream>>>(w1, w1b, 768, 3072);
    castT_kernel<<<dim3(24, 96), 256, 0, stream>>>(w2, w2b, 3072, 768);

    gemm_bf16<128, 0, 1><<<dim3(18, 32), 256, 0, stream>>>(h_bf, wqkvb, bqkv, qkv, 2304, 768);
    vtrans_kernel<<<dim3(64, 2, 24), 256, 0, stream>>>(qkv, vT);
    attn_mfma<<<dim3(32, 12, 2), 256, 0, stream>>>(qkv, vT, obuf);
    gemm_bf16<64, 0, 0><<<dim3(6, 64), 256, 0, stream>>>(obuf, wob, bo + (size_t)l * D_, tmp, 768, 768);
    ln_kernel<<<M_TOK, 256, 0, stream>>>(tmp, h, ln1_g + (size_t)l * D_, ln1_b + (size_t)l * D_, h, h_bf);
    gemm_bf16<128, 1, 1><<<dim3(24, 32), 256, 0, stream>>>(h_bf, w1b, b1 + (size_t)l * F_, ff, 3072, 768);
    gemm_bf16<64, 0, 0><<<dim3(6, 64), 256, 0, stream>>>(ff, w2b, b2 + (size_t)l * D_, tmp, 768, 3072);
    float* out_ln2 = (l == NL_ - 1) ? (float*)d_out : h;
    ln_kernel<<<M_TOK, 256, 0, stream>>>(tmp, h, ln2_g + (size_t)l * D_, ln2_b + (size_t)l * D_, out_ln2, h_bf);
  }
}

// Round 6
// 3186.515 us; speedup vs baseline: 27.8209x; 1.0065x over previous
//
#include <hip/hip_runtime.h>
#include <hip/hip_bf16.h>
#include <stdint.h>

#define B_ 2
#define L_ 2048
#define D_ 768
#define H_ 12
#define F_ 3072
#define NL_ 12
#define K_ 128
#define G_ 16
#define HD_ 64
#define CPG_ 48            // D_/G_
#define M_TOK (B_*L_)      // 4096
#define SCALE_ 0.125f      // HD^-0.5

typedef __hip_bfloat16 bf16;
typedef __bf16 bf16x8 __attribute__((ext_vector_type(8)));
typedef float f32x4 __attribute__((ext_vector_type(4)));

__device__ __forceinline__ void gload16(const void* g, void* l) {
  __builtin_amdgcn_global_load_lds((const __attribute__((address_space(1))) void*)g,
                                   (__attribute__((address_space(3))) void*)l, 16, 0, 0);
}

// ---------------------------------------------------------------- conv weight pre-transpose
// pcw f32 [768][48][128] (d_global, ci, kk) -> wT2 bf16 [g][kk][d(48)][ci(64, zero-pad 48..63)]
__global__ __launch_bounds__(256) void convw_kernel(const float* __restrict__ w,
                                                    bf16* __restrict__ wT2) {
  int idx = blockIdx.x * 256 + threadIdx.x;        // 16*128*48*64 = 6,291,456
  int ci = idx & 63;
  int row = idx >> 6;                              // (g*128+kk)*48 + d
  int d = row % 48;
  int t2 = row / 48;
  int kk = t2 & 127;
  int g = t2 >> 7;
  float v = (ci < 48) ? w[(((size_t)(g * 48 + d) * 48) + ci) * 128 + kk] : 0.f;
  wT2[idx] = __float2bfloat16(v);
}

// ---------------------------------------------------------------- conv via MFMA
__global__ __launch_bounds__(256) void conv_mfma(const float* __restrict__ x,
                                                 const bf16* __restrict__ wT2,
                                                 const float* __restrict__ bias,
                                                 float* __restrict__ out) {
  const int l0 = blockIdx.x * 64, g = blockIdx.y, b = blockIdx.z;
  const int tid = threadIdx.x, w = tid >> 6, lane = tid & 63;
  const int c15 = lane & 15, g4 = lane >> 4;
  __shared__ __align__(16) bf16 win[192 * 72];
  __shared__ __align__(16) bf16 Wl[2 * 48 * 64];

  if (tid < 192) {
    int lg = l0 - 64 + tid;
    char* dst = (char*)win + tid * 144;
    uint4 z4 = {0u, 0u, 0u, 0u};
    if ((unsigned)lg < 2048u) {
      const float* srow = x + ((size_t)(b * 2048 + lg) * 768 + g * 48);
#pragma unroll
      for (int c = 0; c < 6; ++c) {
        float4 v0 = *(const float4*)(srow + c * 8);
        float4 v1 = *(const float4*)(srow + c * 8 + 4);
        union { bf16 h[8]; uint4 u; } uu;
        uu.h[0] = __float2bfloat16(v0.x); uu.h[1] = __float2bfloat16(v0.y);
        uu.h[2] = __float2bfloat16(v0.z); uu.h[3] = __float2bfloat16(v0.w);
        uu.h[4] = __float2bfloat16(v1.x); uu.h[5] = __float2bfloat16(v1.y);
        uu.h[6] = __float2bfloat16(v1.z); uu.h[7] = __float2bfloat16(v1.w);
        *(uint4*)(dst + c * 16) = uu.u;
      }
    } else {
#pragma unroll
      for (int c = 0; c < 6; ++c) *(uint4*)(dst + c * 16) = z4;
    }
    *(uint4*)(dst + 96) = z4;
    *(uint4*)(dst + 112) = z4;
  }
  __syncthreads();

  f32x4 acc[3];
  const f32x4 vzero = {0.f, 0.f, 0.f, 0.f};
  acc[0] = vzero; acc[1] = vzero; acc[2] = vzero;

  const char* wbase = (const char*)wT2 + (size_t)g * 128 * 48 * 128;

  for (int kp = 0; kp < 64; ++kp) {
#pragma unroll
    for (int i = 0; i < 3; ++i) {
      int coff = w * 3072 + i * 1024;
      int c = coff + (lane << 4);
      int row96 = c >> 7;
      int s = row96 / 48;
      int d = row96 - s * 48;
      int cb2 = c & 127;
      gload16(wbase + ((size_t)((2 * kp + s) * 48 + d)) * 128 + (cb2 ^ ((d & 7) << 4)),
              (char*)Wl + coff);
    }
    __syncthreads();
#pragma unroll
    for (int s = 0; s < 2; ++s) {
      int kk = 2 * kp + s;
#pragma unroll
      for (int cb = 0; cb < 2; ++cb) {
        bf16x8 a = *(const bf16x8*)((const char*)win + (w * 16 + c15 + kk) * 144 + cb * 64 + g4 * 16);
#pragma unroll
        for (int ct = 0; ct < 3; ++ct) {
          int d = ct * 16 + c15;
          bf16x8 bfrag = *(const bf16x8*)((const char*)Wl + s * 6144 + d * 128 +
                                          ((cb * 64 + g4 * 16) ^ ((d & 7) << 4)));
          acc[ct] = __builtin_amdgcn_mfma_f32_16x16x32_bf16(a, bfrag, acc[ct], 0, 0, 0);
        }
      }
    }
    __syncthreads();
  }

#pragma unroll
  for (int ct = 0; ct < 3; ++ct) {
    int dg = g * 48 + ct * 16 + c15;
    float bv = bias[dg];
#pragma unroll
    for (int r = 0; r < 4; ++r) {
      int l = l0 + w * 16 + g4 * 4 + r;
      size_t idx = (size_t)(b * 2048 + l) * 768 + dg;
      float vv = acc[ct][r] + bv;
      vv = 0.5f * vv * (1.0f + erff(vv * 0.70710678f));
      out[idx] = x[idx] + vv;
    }
  }
}

// ---------------------------------------------------------------- layernorm (+residual)
__global__ __launch_bounds__(256) void ln_kernel(const float* __restrict__ a,
                                                 const float* __restrict__ r,
                                                 const float* __restrict__ g,
                                                 const float* __restrict__ be,
                                                 float* __restrict__ out,
                                                 bf16* __restrict__ outb) {
  int row = blockIdx.x, tid = threadIdx.x;
  __shared__ float red[256];
  const float* ar = a + (size_t)row * D_;
  float vals[3];
  float s = 0.f;
#pragma unroll
  for (int i = 0; i < 3; ++i) {
    int c = tid + i * 256;
    float vv = ar[c];
    if (r) vv += r[(size_t)row * D_ + c];
    vals[i] = vv; s += vv;
  }
  red[tid] = s; __syncthreads();
  for (int st = 128; st > 0; st >>= 1) {
    if (tid < st) red[tid] += red[tid + st];
    __syncthreads();
  }
  float mean = red[0] * (1.0f / 768.0f);
  __syncthreads();
  float s2 = 0.f;
#pragma unroll
  for (int i = 0; i < 3; ++i) { float d2 = vals[i] - mean; s2 += d2 * d2; }
  red[tid] = s2; __syncthreads();
  for (int st = 128; st > 0; st >>= 1) {
    if (tid < st) red[tid] += red[tid + st];
    __syncthreads();
  }
  float rstd = rsqrtf(red[0] * (1.0f / 768.0f) + 1e-5f);
#pragma unroll
  for (int i = 0; i < 3; ++i) {
    int c = tid + i * 256;
    float ov = (vals[i] - mean) * rstd * g[c] + be[c];
    out[(size_t)row * D_ + c] = ov;
    if (outb) outb[(size_t)row * D_ + c] = __float2bfloat16(ov);
  }
}

// ---------------------------------------------------------------- transpose-cast f32 [R][C] -> bf16 [C][R]
__global__ __launch_bounds__(256) void castT_kernel(const float* __restrict__ src,
                                                    bf16* __restrict__ dst, int R, int C) {
  __shared__ float t[32][33];
  int c0 = blockIdx.x * 32, r0 = blockIdx.y * 32;
  int tx = threadIdx.x & 31, ty = threadIdx.x >> 5;
#pragma unroll
  for (int i = 0; i < 32; i += 8)
    t[ty + i][tx] = src[(size_t)(r0 + ty + i) * C + (c0 + tx)];
  __syncthreads();
#pragma unroll
  for (int i = 0; i < 32; i += 8)
    dst[(size_t)(c0 + ty + i) * R + (r0 + tx)] = __float2bfloat16(t[tx][ty + i]);
}

// qkv fused: dst[2304][768] from wq/wk/wv [768][768]
__global__ __launch_bounds__(256) void castT_qkv_kernel(const float* __restrict__ q,
                                                        const float* __restrict__ k,
                                                        const float* __restrict__ v,
                                                        bf16* __restrict__ dst) {
  int n0 = blockIdx.x * 32, k0 = blockIdx.y * 32;
  const float* src = (n0 < 768) ? q : (n0 < 1536) ? k : v;
  int nn = (n0 >= 1536) ? (n0 - 1536) : (n0 >= 768 ? n0 - 768 : n0);
  __shared__ float t[32][33];
  int tx = threadIdx.x & 31, ty = threadIdx.x >> 5;
#pragma unroll
  for (int i = 0; i < 32; i += 8)
    t[ty + i][tx] = src[(size_t)(k0 + ty + i) * 768 + nn + tx];
  __syncthreads();
#pragma unroll
  for (int i = 0; i < 32; i += 8)
    dst[(size_t)(n0 + ty + i) * 768 + k0 + tx] = __float2bfloat16(t[tx][ty + i]);
}

__global__ __launch_bounds__(256) void bcat_kernel(const float* __restrict__ bq,
                                                   const float* __restrict__ bk,
                                                   const float* __restrict__ bv,
                                                   float* __restrict__ dst) {
  int i = blockIdx.x * 256 + threadIdx.x;
  if (i >= 2304) return;
  dst[i] = (i < 768) ? bq[i] : (i < 1536) ? bk[i - 768] : bv[i - 1536];
}

// v slice of qkv [M][2304] -> vT [(b*12+h)*64 + d][2048]
__global__ __launch_bounds__(256) void vtrans_kernel(const bf16* __restrict__ qkv,
                                                     bf16* __restrict__ vT) {
  int l0 = blockIdx.x * 32, d0 = blockIdx.y * 32, bh = blockIdx.z;
  int b = bh / 12, h = bh % 12;
  __shared__ bf16 t[32][33];
  int tx = threadIdx.x & 31, ty = threadIdx.x >> 5;
#pragma unroll
  for (int i = 0; i < 32; i += 8)
    t[ty + i][tx] = qkv[(size_t)(b * 2048 + l0 + ty + i) * 2304 + 1536 + h * 64 + d0 + tx];
  __syncthreads();
#pragma unroll
  for (int i = 0; i < 32; i += 8)
    vT[((size_t)bh * 64 + d0 + ty + i) * 2048 + l0 + tx] = t[tx][ty + i];
}

// ---------------------------------------------------------------- bf16 MFMA GEMM
template <int BM, int GELU, int BF16OUT>
__global__ __launch_bounds__(256) void gemm_bf16(const bf16* __restrict__ A,
                                                 const bf16* __restrict__ BT,
                                                 const float* __restrict__ bias,
                                                 void* __restrict__ Cout,
                                                 int N, int Kd) {
  constexpr int WM = BM / 2, MF = WM / 16;
  __shared__ bf16 As[BM * 64];
  __shared__ bf16 Bs[128 * 64];
  const int tid = threadIdx.x, w = tid >> 6, lane = tid & 63;
  const int bn = blockIdx.x, bm = blockIdx.y;
  const int wr = w >> 1, wc = w & 1;
  const int c15 = lane & 15, g4 = lane >> 4;
  const int lrow8 = lane >> 3;
  const int cb = (lane & 7) * 16;

  f32x4 acc[MF][4];
  const f32x4 vzero = {0.f, 0.f, 0.f, 0.f};
#pragma unroll
  for (int i = 0; i < MF; ++i)
#pragma unroll
    for (int j = 0; j < 4; ++j) acc[i][j] = vzero;

  const char* Ab = (const char*)A;
  const char* Bb = (const char*)BT;

  for (int k0 = 0; k0 < Kd; k0 += 64) {
#pragma unroll
    for (int i = 0; i < BM / 32; ++i) {
      int t = w + 4 * i;
      int row = t * 8 + lrow8;
      gload16(Ab + ((size_t)(bm * BM + row) * Kd + k0) * 2 + (cb ^ ((row & 7) << 4)),
              (char*)As + t * 1024);
    }
#pragma unroll
    for (int i = 0; i < 4; ++i) {
      int t = w + 4 * i;
      int row = t * 8 + lrow8;
      gload16(Bb + ((size_t)(bn * 128 + row) * Kd + k0) * 2 + (cb ^ ((row & 7) << 4)),
              (char*)Bs + t * 1024);
    }
    __syncthreads();
    bf16x8 af[MF][2], bfr[4][2];
#pragma unroll
    for (int kf = 0; kf < 2; ++kf) {
      int kbyte = kf * 64 + g4 * 16;
#pragma unroll
      for (int mf = 0; mf < MF; ++mf) {
        int row = wr * WM + mf * 16 + c15;
        af[mf][kf] = *(const bf16x8*)((const char*)As + row * 128 + (kbyte ^ ((row & 7) << 4)));
      }
#pragma unroll
      for (int fn = 0; fn < 4; ++fn) {
        int row = wc * 64 + fn * 16 + c15;
        bfr[fn][kf] = *(const bf16x8*)((const char*)Bs + row * 128 + (kbyte ^ ((row & 7) << 4)));
      }
    }
#pragma unroll
    for (int mf = 0; mf < MF; ++mf)
#pragma unroll
      for (int fn = 0; fn < 4; ++fn) {
        acc[mf][fn] = __builtin_amdgcn_mfma_f32_16x16x32_bf16(af[mf][0], bfr[fn][0], acc[mf][fn], 0, 0, 0);
        acc[mf][fn] = __builtin_amdgcn_mfma_f32_16x16x32_bf16(af[mf][1], bfr[fn][1], acc[mf][fn], 0, 0, 0);
      }
    __syncthreads();
  }
#pragma unroll
  for (int fn = 0; fn < 4; ++fn) {
    int col = bn * 128 + wc * 64 + fn * 16 + c15;
    float bv = bias[col];
#pragma unroll
    for (int mf = 0; mf < MF; ++mf) {
#pragma unroll
      for (int r = 0; r < 4; ++r) {
        int row = bm * BM + wr * WM + mf * 16 + g4 * 4 + r;
        float vv = acc[mf][fn][r] + bv;
        if (GELU) vv = 0.5f * vv * (1.0f + erff(vv * 0.70710678f));
        if (BF16OUT) ((bf16*)Cout)[(size_t)row * N + col] = __float2bfloat16(vv);
        else        ((float*)Cout)[(size_t)row * N + col] = vv;
      }
    }
  }
}

// ---------------------------------------------------------------- flash attention v2
// double-buffered K/V prefetch + XCD swizzle + defer-rescale + exp2 softmax + setprio
__global__ __launch_bounds__(256) void attn_mfma(const bf16* __restrict__ qkv,
                                                 const bf16* __restrict__ vT,
                                                 bf16* __restrict__ ob) {
  // XCD-bijective swizzle: 768 blocks, 8 XCDs, 96 per XCD
  int bid = blockIdx.x + 32 * (blockIdx.y + 12 * blockIdx.z);
  int wgid = (bid & 7) * 96 + (bid >> 3);
  const int q0 = (wgid & 31) * 64;
  int bh = wgid >> 5;
  const int h = bh % 12, b = bh / 12;

  const int tid = threadIdx.x, w = tid >> 6, lane = tid & 63;
  const int c15 = lane & 15, g4 = lane >> 4;
  const int lrow8 = lane >> 3;
  const int cb = (lane & 7) * 16;
  __shared__ bf16 Kl[2][4096];
  __shared__ bf16 Vl[2][4096];
  __shared__ bf16 Pl[4096];

  const f32x4 vzero = {0.f, 0.f, 0.f, 0.f};
  const char* qp = (const char*)qkv + (((size_t)(b * 2048 + q0 + w * 16 + c15)) * 2304 + h * 64) * 2;
  bf16x8 qa0 = *(const bf16x8*)(qp + g4 * 16);
  bf16x8 qa1 = *(const bf16x8*)(qp + 64 + g4 * 16);

  f32x4 o[4];
#pragma unroll
  for (int i = 0; i < 4; ++i) o[i] = vzero;
  float m[4] = {-1e30f, -1e30f, -1e30f, -1e30f};
  float lsum[4] = {0.f, 0.f, 0.f, 0.f};
  const float SC2 = 0.18033688f;      // SCALE_ * log2(e)
  const float THR = 11.54f;           // ~8 nats in exp2 domain

  const char* kgb = (const char*)qkv + (((size_t)(b * 2048)) * 2304 + 768 + h * 64) * 2;
  const char* vgb = (const char*)vT + ((size_t)((b * 12 + h) * 64) * 2048) * 2;
  char* Plw = (char*)Pl + w * 2048;

#define STAGE(kt, bufi)                                                                     \
  {                                                                                         \
    char* Kd = (char*)Kl[bufi];                                                             \
    char* Vd = (char*)Vl[bufi];                                                             \
    _Pragma("unroll")                                                                       \
    for (int i = 0; i < 2; ++i) {                                                           \
      int t = w + 4 * i;                                                                    \
      int rr = t * 8 + lrow8;                                                               \
      gload16(kgb + (size_t)((kt) * 64 + rr) * 4608 + (cb ^ ((rr & 7) << 4)), Kd + t * 1024);\
      gload16(vgb + (size_t)rr * 4096 + (size_t)(kt) * 128 + (cb ^ ((rr & 7) << 4)), Vd + t * 1024);\
    }                                                                                       \
  }

  STAGE(0, 0);
  __syncthreads();

  for (int kt = 0; kt < 32; ++kt) {
    int cur = kt & 1;
    if (kt + 1 < 32) STAGE(kt + 1, cur ^ 1);     // prefetch next tile (lands by next barrier)

    const char* Kc = (const char*)Kl[cur];
    const char* Vc = (const char*)Vl[cur];

    // S = Q @ K^T (16 x 64 per wave), exp2 domain
    f32x4 sc[4];
    __builtin_amdgcn_s_setprio(1);
#pragma unroll
    for (int fn = 0; fn < 4; ++fn) {
      int key = fn * 16 + c15;
      const char* kr = Kc + key * 128;
      int sw = (key & 7) << 4;
      bf16x8 kb0 = *(const bf16x8*)(kr + ((g4 * 16) ^ sw));
      bf16x8 kb1 = *(const bf16x8*)(kr + ((64 + g4 * 16) ^ sw));
      f32x4 s = __builtin_amdgcn_mfma_f32_16x16x32_bf16(qa0, kb0, vzero, 0, 0, 0);
      s = __builtin_amdgcn_mfma_f32_16x16x32_bf16(qa1, kb1, s, 0, 0, 0);
      sc[fn] = s;
    }
    __builtin_amdgcn_s_setprio(0);
#pragma unroll
    for (int fn = 0; fn < 4; ++fn)
#pragma unroll
      for (int r = 0; r < 4; ++r) sc[fn][r] *= SC2;

    // row maxes (exp2 domain) + defer-rescale predicate
    float tmx[4];
    int ok = 1;
#pragma unroll
    for (int r = 0; r < 4; ++r) {
      float tm = fmaxf(fmaxf(sc[0][r], sc[1][r]), fmaxf(sc[2][r], sc[3][r]));
      tm = fmaxf(tm, __shfl_xor(tm, 1));
      tm = fmaxf(tm, __shfl_xor(tm, 2));
      tm = fmaxf(tm, __shfl_xor(tm, 4));
      tm = fmaxf(tm, __shfl_xor(tm, 8));
      tmx[r] = tm;
      ok &= (tm <= m[r] + THR) ? 1 : 0;
    }

    if (__all(ok)) {
      // fast path: keep old max, no O/l rescale
#pragma unroll
      for (int r = 0; r < 4; ++r) {
        float rs = 0.f;
#pragma unroll
        for (int fn = 0; fn < 4; ++fn) {
          float p = exp2f(sc[fn][r] - m[r]);
          sc[fn][r] = p;
          rs += p;
        }
        rs += __shfl_xor(rs, 1);
        rs += __shfl_xor(rs, 2);
        rs += __shfl_xor(rs, 4);
        rs += __shfl_xor(rs, 8);
        lsum[r] += rs;
        int row = g4 * 4 + r;
        int sw = (row & 7) << 4;
        char* pr = Plw + row * 128;
#pragma unroll
        for (int fn = 0; fn < 4; ++fn) {
          int colb = (fn * 16 + c15) * 2;
          *(bf16*)(pr + (colb ^ sw)) = __float2bfloat16(sc[fn][r]);
        }
      }
    } else {
#pragma unroll
      for (int r = 0; r < 4; ++r) {
        float mn = fmaxf(m[r], tmx[r]);
        float alpha = exp2f(m[r] - mn);
        m[r] = mn;
        float rs = 0.f;
#pragma unroll
        for (int fn = 0; fn < 4; ++fn) {
          float p = exp2f(sc[fn][r] - mn);
          sc[fn][r] = p;
          rs += p;
        }
        rs += __shfl_xor(rs, 1);
        rs += __shfl_xor(rs, 2);
        rs += __shfl_xor(rs, 4);
        rs += __shfl_xor(rs, 8);
        lsum[r] = lsum[r] * alpha + rs;
        o[0][r] *= alpha; o[1][r] *= alpha; o[2][r] *= alpha; o[3][r] *= alpha;
        int row = g4 * 4 + r;
        int sw = (row & 7) << 4;
        char* pr = Plw + row * 128;
#pragma unroll
        for (int fn = 0; fn < 4; ++fn) {
          int colb = (fn * 16 + c15) * 2;
          *(bf16*)(pr + (colb ^ sw)) = __float2bfloat16(sc[fn][r]);
        }
      }
    }

    // PV: O += P @ V
    {
      const char* pr = Plw + c15 * 128;
      int sw = (c15 & 7) << 4;
      bf16x8 pa0 = *(const bf16x8*)(pr + ((g4 * 16) ^ sw));
      bf16x8 pa1 = *(const bf16x8*)(pr + ((64 + g4 * 16) ^ sw));
      __builtin_amdgcn_s_setprio(1);
#pragma unroll
      for (int fh = 0; fh < 4; ++fh) {
        int hd = fh * 16 + c15;
        const char* vr = Vc + hd * 128;
        int swv = (hd & 7) << 4;
        bf16x8 vb0 = *(const bf16x8*)(vr + ((g4 * 16) ^ swv));
        bf16x8 vb1 = *(const bf16x8*)(vr + ((64 + g4 * 16) ^ swv));
        o[fh] = __builtin_amdgcn_mfma_f32_16x16x32_bf16(pa0, vb0, o[fh], 0, 0, 0);
        o[fh] = __builtin_amdgcn_mfma_f32_16x16x32_bf16(pa1, vb1, o[fh], 0, 0, 0);
      }
      __builtin_amdgcn_s_setprio(0);
    }
    __syncthreads();   // prefetch landed (vmcnt0) + all waves done with cur
  }
#undef STAGE

#pragma unroll
  for (int r = 0; r < 4; ++r) {
    float inv = 1.0f / lsum[r];
    size_t row = (size_t)(b * 2048 + q0 + w * 16 + g4 * 4 + r);
#pragma unroll
    for (int fh = 0; fh < 4; ++fh)
      ob[row * 768 + h * 64 + fh * 16 + c15] = __float2bfloat16(o[fh][r] * inv);
  }
}

// ----------------------------------------------------------------
extern "C" void kernel_launch(void* const* d_in, const int* in_sizes, int n_in,
                              void* d_out, int out_size, void* d_ws, size_t ws_size,
                              hipStream_t stream) {
  const float* x      = (const float*)d_in[0];
  const float* pcw    = (const float*)d_in[1];
  const float* pcb    = (const float*)d_in[2];
  const float* ln0_g  = (const float*)d_in[3];
  const float* ln0_b  = (const float*)d_in[4];
  const float* Wq     = (const float*)d_in[5];
  const float* bq     = (const float*)d_in[6];
  const float* Wk     = (const float*)d_in[7];
  const float* bk     = (const float*)d_in[8];
  const float* Wv     = (const float*)d_in[9];
  const float* bv     = (const float*)d_in[10];
  const float* Wo     = (const float*)d_in[11];
  const float* bo     = (const float*)d_in[12];
  const float* ln1_g  = (const float*)d_in[13];
  const float* ln1_b  = (const float*)d_in[14];
  const float* W1     = (const float*)d_in[15];
  const float* b1     = (const float*)d_in[16];
  const float* W2     = (const float*)d_in[17];
  const float* b2     = (const float*)d_in[18];
  const float* ln2_g  = (const float*)d_in[19];
  const float* ln2_b  = (const float*)d_in[20];

  const size_t MDB = (size_t)M_TOK * D_ * 4;
  char* W = (char*)d_ws;
  float* h    = (float*)W;
  float* tmp  = (float*)(W + MDB);
  char*  big  = W + 2 * MDB;
  bf16*  qkv  = (bf16*)big;
  bf16*  ff   = (bf16*)big;
  bf16*  wT2  = (bf16*)big;
  char* p = W + 2 * MDB + 25165824;
  bf16* h_bf  = (bf16*)p; p += (size_t)M_TOK * D_ * 2;
  bf16* obuf  = (bf16*)p; p += (size_t)M_TOK * D_ * 2;
  bf16* vT    = (bf16*)p; p += (size_t)M_TOK * D_ * 2;
  bf16* wqkvb = (bf16*)p; p += (size_t)2304 * 768 * 2;
  bf16* wob   = (bf16*)p; p += (size_t)768 * 768 * 2;
  bf16* w1b   = (bf16*)p; p += (size_t)3072 * 768 * 2;
  bf16* w2b   = (bf16*)p; p += (size_t)768 * 3072 * 2;
  float* bqkv = (float*)p;

  convw_kernel<<<24576, 256, 0, stream>>>(pcw, wT2);
  conv_mfma<<<dim3(32, 16, 2), 256, 0, stream>>>(x, wT2, pcb, tmp);
  ln_kernel<<<M_TOK, 256, 0, stream>>>(tmp, nullptr, ln0_g, ln0_b, h, h_bf);

  for (int l = 0; l < NL_; ++l) {
    const float* wq = Wq + (size_t)l * D_ * D_;
    const float* wk = Wk + (size_t)l * D_ * D_;
    const float* wv = Wv + (size_t)l * D_ * D_;
    const float* wo = Wo + (size_t)l * D_ * D_;
    const float* w1 = W1 + (size_t)l * D_ * F_;
    const float* w2 = W2 + (size_t)l * F_ * D_;

    castT_qkv_kernel<<<dim3(72, 24), 256, 0, stream>>>(wq, wk, wv, wqkvb);
    bcat_kernel<<<9, 256, 0, stream>>>(bq + (size_t)l * D_, bk + (size_t)l * D_, bv + (size_t)l * D_, bqkv);
    castT_kernel<<<dim3(24, 24), 256, 0, stream>>>(wo, wob, 768, 768);
    castT_kernel<<<dim3(96, 24), 256, 0, stream>>>(w1, w1b, 768, 3072);
    castT_kernel<<<dim3(24, 96), 256, 0, stream>>>(w2, w2b, 3072, 768);

    gemm_bf16<128, 0, 1><<<dim3(18, 32), 256, 0, stream>>>(h_bf, wqkvb, bqkv, qkv, 2304, 768);
    vtrans_kernel<<<dim3(64, 2, 24), 256, 0, stream>>>(qkv, vT);
    attn_mfma<<<dim3(32, 12, 2), 256, 0, stream>>>(qkv, vT, obuf);
    gemm_bf16<64, 0, 0><<<dim3(6, 64), 256, 0, stream>>>(obuf, wob, bo + (size_t)l * D_, tmp, 768, 768);
    ln_kernel<<<M_TOK, 256, 0, stream>>>(tmp, h, ln1_g + (size_t)l * D_, ln1_b + (size_t)l * D_, h, h_bf);
    gemm_bf16<128, 1, 1><<<dim3(24, 32), 256, 0, stream>>>(h_bf, w1b, b1 + (size_t)l * F_, ff, 3072, 768);
    gemm_bf16<64, 0, 0><<<dim3(6, 64), 256, 0, stream>>>(ff, w2b, b2 + (size_t)l * D_, tmp, 768, 3072);
    float* out_ln2 = (l == NL_ - 1) ? (float*)d_out : h;
    ln_kernel<<<M_TOK, 256, 0, stream>>>(tmp, h, ln2_g + (size_t)l * D_, ln2_b + (size_t)l * D_, out_ln2, h_bf);
  }
}

// Round 7
// 2661.654 us; speedup vs baseline: 33.3070x; 1.1972x over previous
//
#include <hip/hip_runtime.h>
#include <hip/hip_bf16.h>
#include <stdint.h>

#define B_ 2
#define L_ 2048
#define D_ 768
#define H_ 12
#define F_ 3072
#define NL_ 12
#define K_ 128
#define G_ 16
#define HD_ 64
#define CPG_ 48            // D_/G_
#define M_TOK (B_*L_)      // 4096
#define SCALE_ 0.125f      // HD^-0.5

typedef __hip_bfloat16 bf16;
typedef __bf16 bf16x8 __attribute__((ext_vector_type(8)));
typedef float f32x4 __attribute__((ext_vector_type(4)));

__device__ __forceinline__ void gload16(const void* g, void* l) {
  __builtin_amdgcn_global_load_lds((const __attribute__((address_space(1))) void*)g,
                                   (__attribute__((address_space(3))) void*)l, 16, 0, 0);
}

// ---------------------------------------------------------------- conv weight pre-transpose
__global__ __launch_bounds__(256) void convw_kernel(const float* __restrict__ w,
                                                    bf16* __restrict__ wT2) {
  int idx = blockIdx.x * 256 + threadIdx.x;        // 16*128*48*64
  int ci = idx & 63;
  int row = idx >> 6;
  int d = row % 48;
  int t2 = row / 48;
  int kk = t2 & 127;
  int g = t2 >> 7;
  float v = (ci < 48) ? w[(((size_t)(g * 48 + d) * 48) + ci) * 128 + kk] : 0.f;
  wT2[idx] = __float2bfloat16(v);
}

// ---------------------------------------------------------------- conv via MFMA
__global__ __launch_bounds__(256) void conv_mfma(const float* __restrict__ x,
                                                 const bf16* __restrict__ wT2,
                                                 const float* __restrict__ bias,
                                                 float* __restrict__ out) {
  const int l0 = blockIdx.x * 64, g = blockIdx.y, b = blockIdx.z;
  const int tid = threadIdx.x, w = tid >> 6, lane = tid & 63;
  const int c15 = lane & 15, g4 = lane >> 4;
  __shared__ __align__(16) bf16 win[192 * 72];
  __shared__ __align__(16) bf16 Wl[2 * 48 * 64];

  if (tid < 192) {
    int lg = l0 - 64 + tid;
    char* dst = (char*)win + tid * 144;
    uint4 z4 = {0u, 0u, 0u, 0u};
    if ((unsigned)lg < 2048u) {
      const float* srow = x + ((size_t)(b * 2048 + lg) * 768 + g * 48);
#pragma unroll
      for (int c = 0; c < 6; ++c) {
        float4 v0 = *(const float4*)(srow + c * 8);
        float4 v1 = *(const float4*)(srow + c * 8 + 4);
        union { bf16 h[8]; uint4 u; } uu;
        uu.h[0] = __float2bfloat16(v0.x); uu.h[1] = __float2bfloat16(v0.y);
        uu.h[2] = __float2bfloat16(v0.z); uu.h[3] = __float2bfloat16(v0.w);
        uu.h[4] = __float2bfloat16(v1.x); uu.h[5] = __float2bfloat16(v1.y);
        uu.h[6] = __float2bfloat16(v1.z); uu.h[7] = __float2bfloat16(v1.w);
        *(uint4*)(dst + c * 16) = uu.u;
      }
    } else {
#pragma unroll
      for (int c = 0; c < 6; ++c) *(uint4*)(dst + c * 16) = z4;
    }
    *(uint4*)(dst + 96) = z4;
    *(uint4*)(dst + 112) = z4;
  }
  __syncthreads();

  f32x4 acc[3];
  const f32x4 vzero = {0.f, 0.f, 0.f, 0.f};
  acc[0] = vzero; acc[1] = vzero; acc[2] = vzero;

  const char* wbase = (const char*)wT2 + (size_t)g * 128 * 48 * 128;

  for (int kp = 0; kp < 64; ++kp) {
#pragma unroll
    for (int i = 0; i < 3; ++i) {
      int coff = w * 3072 + i * 1024;
      int c = coff + (lane << 4);
      int row96 = c >> 7;
      int s = row96 / 48;
      int d = row96 - s * 48;
      int cb2 = c & 127;
      gload16(wbase + ((size_t)((2 * kp + s) * 48 + d)) * 128 + (cb2 ^ ((d & 7) << 4)),
              (char*)Wl + coff);
    }
    __syncthreads();
#pragma unroll
    for (int s = 0; s < 2; ++s) {
      int kk = 2 * kp + s;
#pragma unroll
      for (int cb = 0; cb < 2; ++cb) {
        bf16x8 a = *(const bf16x8*)((const char*)win + (w * 16 + c15 + kk) * 144 + cb * 64 + g4 * 16);
#pragma unroll
        for (int ct = 0; ct < 3; ++ct) {
          int d = ct * 16 + c15;
          bf16x8 bfrag = *(const bf16x8*)((const char*)Wl + s * 6144 + d * 128 +
                                          ((cb * 64 + g4 * 16) ^ ((d & 7) << 4)));
          acc[ct] = __builtin_amdgcn_mfma_f32_16x16x32_bf16(a, bfrag, acc[ct], 0, 0, 0);
        }
      }
    }
    __syncthreads();
  }

#pragma unroll
  for (int ct = 0; ct < 3; ++ct) {
    int dg = g * 48 + ct * 16 + c15;
    float bv = bias[dg];
#pragma unroll
    for (int r = 0; r < 4; ++r) {
      int l = l0 + w * 16 + g4 * 4 + r;
      size_t idx = (size_t)(b * 2048 + l) * 768 + dg;
      float vv = acc[ct][r] + bv;
      vv = 0.5f * vv * (1.0f + erff(vv * 0.70710678f));
      out[idx] = x[idx] + vv;
    }
  }
}

// ---------------------------------------------------------------- layernorm (+residual)
__global__ __launch_bounds__(256) void ln_kernel(const float* __restrict__ a,
                                                 const float* __restrict__ r,
                                                 const float* __restrict__ g,
                                                 const float* __restrict__ be,
                                                 float* __restrict__ out,
                                                 bf16* __restrict__ outb) {
  int row = blockIdx.x, tid = threadIdx.x;
  __shared__ float red[256];
  const float* ar = a + (size_t)row * D_;
  float vals[3];
  float s = 0.f;
#pragma unroll
  for (int i = 0; i < 3; ++i) {
    int c = tid + i * 256;
    float vv = ar[c];
    if (r) vv += r[(size_t)row * D_ + c];
    vals[i] = vv; s += vv;
  }
  red[tid] = s; __syncthreads();
  for (int st = 128; st > 0; st >>= 1) {
    if (tid < st) red[tid] += red[tid + st];
    __syncthreads();
  }
  float mean = red[0] * (1.0f / 768.0f);
  __syncthreads();
  float s2 = 0.f;
#pragma unroll
  for (int i = 0; i < 3; ++i) { float d2 = vals[i] - mean; s2 += d2 * d2; }
  red[tid] = s2; __syncthreads();
  for (int st = 128; st > 0; st >>= 1) {
    if (tid < st) red[tid] += red[tid + st];
    __syncthreads();
  }
  float rstd = rsqrtf(red[0] * (1.0f / 768.0f) + 1e-5f);
#pragma unroll
  for (int i = 0; i < 3; ++i) {
    int c = tid + i * 256;
    float ov = (vals[i] - mean) * rstd * g[c] + be[c];
    out[(size_t)row * D_ + c] = ov;
    if (outb) outb[(size_t)row * D_ + c] = __float2bfloat16(ov);
  }
}

// ---------------------------------------------------------------- transpose-cast f32 [R][C] -> bf16 [C][R]
__global__ __launch_bounds__(256) void castT_kernel(const float* __restrict__ src,
                                                    bf16* __restrict__ dst, int R, int C) {
  __shared__ float t[32][33];
  int c0 = blockIdx.x * 32, r0 = blockIdx.y * 32;
  int tx = threadIdx.x & 31, ty = threadIdx.x >> 5;
#pragma unroll
  for (int i = 0; i < 32; i += 8)
    t[ty + i][tx] = src[(size_t)(r0 + ty + i) * C + (c0 + tx)];
  __syncthreads();
#pragma unroll
  for (int i = 0; i < 32; i += 8)
    dst[(size_t)(c0 + ty + i) * R + (r0 + tx)] = __float2bfloat16(t[tx][ty + i]);
}

__global__ __launch_bounds__(256) void castT_qkv_kernel(const float* __restrict__ q,
                                                        const float* __restrict__ k,
                                                        const float* __restrict__ v,
                                                        bf16* __restrict__ dst) {
  int n0 = blockIdx.x * 32, k0 = blockIdx.y * 32;
  const float* src = (n0 < 768) ? q : (n0 < 1536) ? k : v;
  int nn = (n0 >= 1536) ? (n0 - 1536) : (n0 >= 768 ? n0 - 768 : n0);
  __shared__ float t[32][33];
  int tx = threadIdx.x & 31, ty = threadIdx.x >> 5;
#pragma unroll
  for (int i = 0; i < 32; i += 8)
    t[ty + i][tx] = src[(size_t)(k0 + ty + i) * 768 + nn + tx];
  __syncthreads();
#pragma unroll
  for (int i = 0; i < 32; i += 8)
    dst[(size_t)(n0 + ty + i) * 768 + k0 + tx] = __float2bfloat16(t[tx][ty + i]);
}

__global__ __launch_bounds__(256) void bcat_kernel(const float* __restrict__ bq,
                                                   const float* __restrict__ bk,
                                                   const float* __restrict__ bv,
                                                   float* __restrict__ dst) {
  int i = blockIdx.x * 256 + threadIdx.x;
  if (i >= 2304) return;
  dst[i] = (i < 768) ? bq[i] : (i < 1536) ? bk[i - 768] : bv[i - 1536];
}

// v slice of qkv [M][2304] -> vT [(b*12+h)*64 + d][2048]
__global__ __launch_bounds__(256) void vtrans_kernel(const bf16* __restrict__ qkv,
                                                     bf16* __restrict__ vT) {
  int l0 = blockIdx.x * 32, d0 = blockIdx.y * 32, bh = blockIdx.z;
  int b = bh / 12, h = bh % 12;
  __shared__ bf16 t[32][33];
  int tx = threadIdx.x & 31, ty = threadIdx.x >> 5;
#pragma unroll
  for (int i = 0; i < 32; i += 8)
    t[ty + i][tx] = qkv[(size_t)(b * 2048 + l0 + ty + i) * 2304 + 1536 + h * 64 + d0 + tx];
  __syncthreads();
#pragma unroll
  for (int i = 0; i < 32; i += 8)
    vT[((size_t)bh * 64 + d0 + ty + i) * 2048 + l0 + tx] = t[tx][ty + i];
}

// ---------------------------------------------------------------- bf16 MFMA GEMM (+XCD swizzle)
template <int BM, int GELU, int BF16OUT>
__global__ __launch_bounds__(256) void gemm_bf16(const bf16* __restrict__ A,
                                                 const bf16* __restrict__ BT,
                                                 const float* __restrict__ bias,
                                                 void* __restrict__ Cout,
                                                 int N, int Kd) {
  constexpr int WM = BM / 2, MF = WM / 16;
  __shared__ bf16 As[BM * 64];
  __shared__ bf16 Bs[128 * 64];
  const int tid = threadIdx.x, w = tid >> 6, lane = tid & 63;
  // XCD-bijective swizzle (grid sizes here are all % 8 == 0)
  int gx = gridDim.x;
  int flat = blockIdx.x + gx * blockIdx.y;
  int cpx = (gx * gridDim.y) >> 3;
  int sw = (flat & 7) * cpx + (flat >> 3);
  const int bn = sw % gx, bm = sw / gx;
  const int wr = w >> 1, wc = w & 1;
  const int c15 = lane & 15, g4 = lane >> 4;
  const int lrow8 = lane >> 3;
  const int cb = (lane & 7) * 16;

  f32x4 acc[MF][4];
  const f32x4 vzero = {0.f, 0.f, 0.f, 0.f};
#pragma unroll
  for (int i = 0; i < MF; ++i)
#pragma unroll
    for (int j = 0; j < 4; ++j) acc[i][j] = vzero;

  const char* Ab = (const char*)A;
  const char* Bb = (const char*)BT;

  for (int k0 = 0; k0 < Kd; k0 += 64) {
#pragma unroll
    for (int i = 0; i < BM / 32; ++i) {
      int t = w + 4 * i;
      int row = t * 8 + lrow8;
      gload16(Ab + ((size_t)(bm * BM + row) * Kd + k0) * 2 + (cb ^ ((row & 7) << 4)),
              (char*)As + t * 1024);
    }
#pragma unroll
    for (int i = 0; i < 4; ++i) {
      int t = w + 4 * i;
      int row = t * 8 + lrow8;
      gload16(Bb + ((size_t)(bn * 128 + row) * Kd + k0) * 2 + (cb ^ ((row & 7) << 4)),
              (char*)Bs + t * 1024);
    }
    __syncthreads();
    bf16x8 af[MF][2], bfr[4][2];
#pragma unroll
    for (int kf = 0; kf < 2; ++kf) {
      int kbyte = kf * 64 + g4 * 16;
#pragma unroll
      for (int mf = 0; mf < MF; ++mf) {
        int row = wr * WM + mf * 16 + c15;
        af[mf][kf] = *(const bf16x8*)((const char*)As + row * 128 + (kbyte ^ ((row & 7) << 4)));
      }
#pragma unroll
      for (int fn = 0; fn < 4; ++fn) {
        int row = wc * 64 + fn * 16 + c15;
        bfr[fn][kf] = *(const bf16x8*)((const char*)Bs + row * 128 + (kbyte ^ ((row & 7) << 4)));
      }
    }
    __builtin_amdgcn_s_setprio(1);
#pragma unroll
    for (int mf = 0; mf < MF; ++mf)
#pragma unroll
      for (int fn = 0; fn < 4; ++fn) {
        acc[mf][fn] = __builtin_amdgcn_mfma_f32_16x16x32_bf16(af[mf][0], bfr[fn][0], acc[mf][fn], 0, 0, 0);
        acc[mf][fn] = __builtin_amdgcn_mfma_f32_16x16x32_bf16(af[mf][1], bfr[fn][1], acc[mf][fn], 0, 0, 0);
      }
    __builtin_amdgcn_s_setprio(0);
    __syncthreads();
  }
#pragma unroll
  for (int fn = 0; fn < 4; ++fn) {
    int col = bn * 128 + wc * 64 + fn * 16 + c15;
    float bv = bias[col];
#pragma unroll
    for (int mf = 0; mf < MF; ++mf) {
#pragma unroll
      for (int r = 0; r < 4; ++r) {
        int row = bm * BM + wr * WM + mf * 16 + g4 * 4 + r;
        float vv = acc[mf][fn][r] + bv;
        if (GELU) vv = 0.5f * vv * (1.0f + erff(vv * 0.70710678f));
        if (BF16OUT) ((bf16*)Cout)[(size_t)row * N + col] = __float2bfloat16(vv);
        else        ((float*)Cout)[(size_t)row * N + col] = vv;
      }
    }
  }
}

// ---------------------------------------------------------------- flash attention v3
// dbuf prefetch + XCD swizzle + shuffle-free fast-path softmax + lsum-via-MFMA(ones)
__global__ __launch_bounds__(256) void attn_mfma(const bf16* __restrict__ qkv,
                                                 const bf16* __restrict__ vT,
                                                 bf16* __restrict__ ob) {
  int bid = blockIdx.x + 32 * (blockIdx.y + 12 * blockIdx.z);
  int wgid = (bid & 7) * 96 + (bid >> 3);
  const int q0 = (wgid & 31) * 64;
  int bh = wgid >> 5;
  const int h = bh % 12, b = bh / 12;

  const int tid = threadIdx.x, w = tid >> 6, lane = tid & 63;
  const int c15 = lane & 15, g4 = lane >> 4;
  const int lrow8 = lane >> 3;
  const int cb = (lane & 7) * 16;
  __shared__ bf16 Kl[2][4096];
  __shared__ bf16 Vl[2][4096];
  __shared__ bf16 Pl[4096];

  const f32x4 vzero = {0.f, 0.f, 0.f, 0.f};
  const char* qp = (const char*)qkv + (((size_t)(b * 2048 + q0 + w * 16 + c15)) * 2304 + h * 64) * 2;
  bf16x8 qa0 = *(const bf16x8*)(qp + g4 * 16);
  bf16x8 qa1 = *(const bf16x8*)(qp + 64 + g4 * 16);

  bf16x8 b_one;
#pragma unroll
  for (int i = 0; i < 8; ++i) b_one[i] = (__bf16)1.0f;

  f32x4 o[4], o5;
#pragma unroll
  for (int i = 0; i < 4; ++i) o[i] = vzero;
  o5 = vzero;                          // row-sum accumulator (lsum)
  float m[4] = {-1e30f, -1e30f, -1e30f, -1e30f};
  const float SC2 = 0.18033688f;       // SCALE_ * log2(e)
  const float THR = 11.54f;            // ~8 nats in exp2 domain

  const char* kgb = (const char*)qkv + (((size_t)(b * 2048)) * 2304 + 768 + h * 64) * 2;
  const char* vgb = (const char*)vT + ((size_t)((b * 12 + h) * 64) * 2048) * 2;
  char* Plw = (char*)Pl + w * 2048;

#define STAGE(kt, bufi)                                                                     \
  {                                                                                         \
    char* Kd = (char*)Kl[bufi];                                                             \
    char* Vd = (char*)Vl[bufi];                                                             \
    _Pragma("unroll")                                                                       \
    for (int i = 0; i < 2; ++i) {                                                           \
      int t = w + 4 * i;                                                                    \
      int rr = t * 8 + lrow8;                                                               \
      gload16(kgb + (size_t)((kt) * 64 + rr) * 4608 + (cb ^ ((rr & 7) << 4)), Kd + t * 1024);\
      gload16(vgb + (size_t)rr * 4096 + (size_t)(kt) * 128 + (cb ^ ((rr & 7) << 4)), Vd + t * 1024);\
    }                                                                                       \
  }

  STAGE(0, 0);
  __syncthreads();

  for (int kt = 0; kt < 32; ++kt) {
    int cur = kt & 1;
    if (kt + 1 < 32) STAGE(kt + 1, cur ^ 1);

    const char* Kc = (const char*)Kl[cur];
    const char* Vc = (const char*)Vl[cur];

    // S = Q @ K^T (raw logits; scale folded into exp via fma)
    f32x4 sc[4];
    __builtin_amdgcn_s_setprio(1);
#pragma unroll
    for (int fn = 0; fn < 4; ++fn) {
      int key = fn * 16 + c15;
      const char* kr = Kc + key * 128;
      int sw = (key & 7) << 4;
      bf16x8 kb0 = *(const bf16x8*)(kr + ((g4 * 16) ^ sw));
      bf16x8 kb1 = *(const bf16x8*)(kr + ((64 + g4 * 16) ^ sw));
      f32x4 s = __builtin_amdgcn_mfma_f32_16x16x32_bf16(qa0, kb0, vzero, 0, 0, 0);
      s = __builtin_amdgcn_mfma_f32_16x16x32_bf16(qa1, kb1, s, 0, 0, 0);
      sc[fn] = s;
    }
    __builtin_amdgcn_s_setprio(0);

    // per-lane row maxes (raw domain) + shuffle-free defer predicate
    float pm[4];
    int ok = 1;
#pragma unroll
    for (int r = 0; r < 4; ++r) {
      pm[r] = fmaxf(fmaxf(sc[0][r], sc[1][r]), fmaxf(sc[2][r], sc[3][r]));
      ok &= (pm[r] * SC2 <= m[r] + THR) ? 1 : 0;
    }

    if (!__all(ok)) {
      // rescale path (rare): full shfl max-reduce, update m, rescale O and o5
#pragma unroll
      for (int r = 0; r < 4; ++r) {
        float tm = pm[r];
        tm = fmaxf(tm, __shfl_xor(tm, 1));
        tm = fmaxf(tm, __shfl_xor(tm, 2));
        tm = fmaxf(tm, __shfl_xor(tm, 4));
        tm = fmaxf(tm, __shfl_xor(tm, 8));
        float mn = fmaxf(m[r], tm * SC2);
        float alpha = exp2f(m[r] - mn);
        m[r] = mn;
        o[0][r] *= alpha; o[1][r] *= alpha; o[2][r] *= alpha; o[3][r] *= alpha;
        o5[r] *= alpha;
      }
    }

    // P = exp2(S*SC2 - m) -> LDS (bf16)
#pragma unroll
    for (int r = 0; r < 4; ++r) {
      int row = g4 * 4 + r;
      int swp = (row & 7) << 4;
      char* pr = Plw + row * 128;
#pragma unroll
      for (int fn = 0; fn < 4; ++fn) {
        float p = exp2f(fmaf(sc[fn][r], SC2, -m[r]));
        int colb = (fn * 16 + c15) * 2;
        *(bf16*)(pr + (colb ^ swp)) = __float2bfloat16(p);
      }
    }

    // PV: O += P @ V ; o5 += P @ 1 (row-sum on the matrix pipe)
    {
      const char* pr = Plw + c15 * 128;
      int sw = (c15 & 7) << 4;
      bf16x8 pa0 = *(const bf16x8*)(pr + ((g4 * 16) ^ sw));
      bf16x8 pa1 = *(const bf16x8*)(pr + ((64 + g4 * 16) ^ sw));
      __builtin_amdgcn_s_setprio(1);
#pragma unroll
      for (int fh = 0; fh < 4; ++fh) {
        int hd = fh * 16 + c15;
        const char* vr = Vc + hd * 128;
        int swv = (hd & 7) << 4;
        bf16x8 vb0 = *(const bf16x8*)(vr + ((g4 * 16) ^ swv));
        bf16x8 vb1 = *(const bf16x8*)(vr + ((64 + g4 * 16) ^ swv));
        o[fh] = __builtin_amdgcn_mfma_f32_16x16x32_bf16(pa0, vb0, o[fh], 0, 0, 0);
        o[fh] = __builtin_amdgcn_mfma_f32_16x16x32_bf16(pa1, vb1, o[fh], 0, 0, 0);
      }
      o5 = __builtin_amdgcn_mfma_f32_16x16x32_bf16(pa0, b_one, o5, 0, 0, 0);
      o5 = __builtin_amdgcn_mfma_f32_16x16x32_bf16(pa1, b_one, o5, 0, 0, 0);
      __builtin_amdgcn_s_setprio(0);
    }
    __syncthreads();
  }
#undef STAGE

#pragma unroll
  for (int r = 0; r < 4; ++r) {
    float inv = 1.0f / o5[r];
    size_t row = (size_t)(b * 2048 + q0 + w * 16 + g4 * 4 + r);
#pragma unroll
    for (int fh = 0; fh < 4; ++fh)
      ob[row * 768 + h * 64 + fh * 16 + c15] = __float2bfloat16(o[fh][r] * inv);
  }
}

// ----------------------------------------------------------------
extern "C" void kernel_launch(void* const* d_in, const int* in_sizes, int n_in,
                              void* d_out, int out_size, void* d_ws, size_t ws_size,
                              hipStream_t stream) {
  const float* x      = (const float*)d_in[0];
  const float* pcw    = (const float*)d_in[1];
  const float* pcb    = (const float*)d_in[2];
  const float* ln0_g  = (const float*)d_in[3];
  const float* ln0_b  = (const float*)d_in[4];
  const float* Wq     = (const float*)d_in[5];
  const float* bq     = (const float*)d_in[6];
  const float* Wk     = (const float*)d_in[7];
  const float* bk     = (const float*)d_in[8];
  const float* Wv     = (const float*)d_in[9];
  const float* bv     = (const float*)d_in[10];
  const float* Wo     = (const float*)d_in[11];
  const float* bo     = (const float*)d_in[12];
  const float* ln1_g  = (const float*)d_in[13];
  const float* ln1_b  = (const float*)d_in[14];
  const float* W1     = (const float*)d_in[15];
  const float* b1     = (const float*)d_in[16];
  const float* W2     = (const float*)d_in[17];
  const float* b2     = (const float*)d_in[18];
  const float* ln2_g  = (const float*)d_in[19];
  const float* ln2_b  = (const float*)d_in[20];

  const size_t MDB = (size_t)M_TOK * D_ * 4;
  char* W = (char*)d_ws;
  float* h    = (float*)W;
  float* tmp  = (float*)(W + MDB);
  char*  big  = W + 2 * MDB;
  bf16*  qkv  = (bf16*)big;
  bf16*  ff   = (bf16*)big;
  bf16*  wT2  = (bf16*)big;
  char* p = W + 2 * MDB + 25165824;
  bf16* h_bf  = (bf16*)p; p += (size_t)M_TOK * D_ * 2;
  bf16* obuf  = (bf16*)p; p += (size_t)M_TOK * D_ * 2;
  bf16* vT    = (bf16*)p; p += (size_t)M_TOK * D_ * 2;
  bf16* wqkvb = (bf16*)p; p += (size_t)2304 * 768 * 2;
  bf16* wob   = (bf16*)p; p += (size_t)768 * 768 * 2;
  bf16* w1b   = (bf16*)p; p += (size_t)3072 * 768 * 2;
  bf16* w2b   = (bf16*)p; p += (size_t)768 * 3072 * 2;
  float* bqkv = (float*)p;

  convw_kernel<<<24576, 256, 0, stream>>>(pcw, wT2);
  conv_mfma<<<dim3(32, 16, 2), 256, 0, stream>>>(x, wT2, pcb, tmp);
  ln_kernel<<<M_TOK, 256, 0, stream>>>(tmp, nullptr, ln0_g, ln0_b, h, h_bf);

  for (int l = 0; l < NL_; ++l) {
    const float* wq = Wq + (size_t)l * D_ * D_;
    const float* wk = Wk + (size_t)l * D_ * D_;
    const float* wv = Wv + (size_t)l * D_ * D_;
    const float* wo = Wo + (size_t)l * D_ * D_;
    const float* w1 = W1 + (size_t)l * D_ * F_;
    const float* w2 = W2 + (size_t)l * F_ * D_;

    castT_qkv_kernel<<<dim3(72, 24), 256, 0, stream>>>(wq, wk, wv, wqkvb);
    bcat_kernel<<<9, 256, 0, stream>>>(bq + (size_t)l * D_, bk + (size_t)l * D_, bv + (size_t)l * D_, bqkv);
    castT_kernel<<<dim3(24, 24), 256, 0, stream>>>(wo, wob, 768, 768);
    castT_kernel<<<dim3(96, 24), 256, 0, stream>>>(w1, w1b, 768, 3072);
    castT_kernel<<<dim3(24, 96), 256, 0, stream>>>(w2, w2b, 3072, 768);

    gemm_bf16<128, 0, 1><<<dim3(18, 32), 256, 0, stream>>>(h_bf, wqkvb, bqkv, qkv, 2304, 768);
    vtrans_kernel<<<dim3(64, 2, 24), 256, 0, stream>>>(qkv, vT);
    attn_mfma<<<dim3(32, 12, 2), 256, 0, stream>>>(qkv, vT, obuf);
    gemm_bf16<64, 0, 0><<<dim3(6, 64), 256, 0, stream>>>(obuf, wob, bo + (size_t)l * D_, tmp, 768, 768);
    ln_kernel<<<M_TOK, 256, 0, stream>>>(tmp, h, ln1_g + (size_t)l * D_, ln1_b + (size_t)l * D_, h, h_bf);
    gemm_bf16<128, 1, 1><<<dim3(24, 32), 256, 0, stream>>>(h_bf, w1b, b1 + (size_t)l * F_, ff, 3072, 768);
    gemm_bf16<64, 0, 0><<<dim3(6, 64), 256, 0, stream>>>(ff, w2b, b2 + (size_t)l * D_, tmp, 768, 3072);
    float* out_ln2 = (l == NL_ - 1) ? (float*)d_out : h;
    ln_kernel<<<M_TOK, 256, 0, stream>>>(tmp, h, ln2_g + (size_t)l * D_, ln2_b + (size_t)l * D_, out_ln2, h_bf);
  }
}

// Round 8
// 2389.968 us; speedup vs baseline: 37.0932x; 1.1137x over previous
//
#include <hip/hip_runtime.h>
#include <hip/hip_bf16.h>
#include <stdint.h>

#define B_ 2
#define L_ 2048
#define D_ 768
#define H_ 12
#define F_ 3072
#define NL_ 12
#define K_ 128
#define G_ 16
#define HD_ 64
#define CPG_ 48            // D_/G_
#define M_TOK (B_*L_)      // 4096
#define SCALE_ 0.125f      // HD^-0.5

typedef __hip_bfloat16 bf16;
typedef __bf16 bf16x8 __attribute__((ext_vector_type(8)));
typedef float f32x4 __attribute__((ext_vector_type(4)));

__device__ __forceinline__ void gload16(const void* g, void* l) {
  __builtin_amdgcn_global_load_lds((const __attribute__((address_space(1))) void*)g,
                                   (__attribute__((address_space(3))) void*)l, 16, 0, 0);
}

// ---------------------------------------------------------------- conv weight pre-transpose
__global__ __launch_bounds__(256) void convw_kernel(const float* __restrict__ w,
                                                    bf16* __restrict__ wT2) {
  int idx = blockIdx.x * 256 + threadIdx.x;        // 16*128*48*64
  int ci = idx & 63;
  int row = idx >> 6;
  int d = row % 48;
  int t2 = row / 48;
  int kk = t2 & 127;
  int g = t2 >> 7;
  float v = (ci < 48) ? w[(((size_t)(g * 48 + d) * 48) + ci) * 128 + kk] : 0.f;
  wT2[idx] = __float2bfloat16(v);
}

// ---------------------------------------------------------------- conv via MFMA
__global__ __launch_bounds__(256) void conv_mfma(const float* __restrict__ x,
                                                 const bf16* __restrict__ wT2,
                                                 const float* __restrict__ bias,
                                                 float* __restrict__ out) {
  const int l0 = blockIdx.x * 64, g = blockIdx.y, b = blockIdx.z;
  const int tid = threadIdx.x, w = tid >> 6, lane = tid & 63;
  const int c15 = lane & 15, g4 = lane >> 4;
  __shared__ __align__(16) bf16 win[192 * 72];
  __shared__ __align__(16) bf16 Wl[2 * 48 * 64];

  if (tid < 192) {
    int lg = l0 - 64 + tid;
    char* dst = (char*)win + tid * 144;
    uint4 z4 = {0u, 0u, 0u, 0u};
    if ((unsigned)lg < 2048u) {
      const float* srow = x + ((size_t)(b * 2048 + lg) * 768 + g * 48);
#pragma unroll
      for (int c = 0; c < 6; ++c) {
        float4 v0 = *(const float4*)(srow + c * 8);
        float4 v1 = *(const float4*)(srow + c * 8 + 4);
        union { bf16 h[8]; uint4 u; } uu;
        uu.h[0] = __float2bfloat16(v0.x); uu.h[1] = __float2bfloat16(v0.y);
        uu.h[2] = __float2bfloat16(v0.z); uu.h[3] = __float2bfloat16(v0.w);
        uu.h[4] = __float2bfloat16(v1.x); uu.h[5] = __float2bfloat16(v1.y);
        uu.h[6] = __float2bfloat16(v1.z); uu.h[7] = __float2bfloat16(v1.w);
        *(uint4*)(dst + c * 16) = uu.u;
      }
    } else {
#pragma unroll
      for (int c = 0; c < 6; ++c) *(uint4*)(dst + c * 16) = z4;
    }
    *(uint4*)(dst + 96) = z4;
    *(uint4*)(dst + 112) = z4;
  }
  __syncthreads();

  f32x4 acc[3];
  const f32x4 vzero = {0.f, 0.f, 0.f, 0.f};
  acc[0] = vzero; acc[1] = vzero; acc[2] = vzero;

  const char* wbase = (const char*)wT2 + (size_t)g * 128 * 48 * 128;

  for (int kp = 0; kp < 64; ++kp) {
#pragma unroll
    for (int i = 0; i < 3; ++i) {
      int coff = w * 3072 + i * 1024;
      int c = coff + (lane << 4);
      int row96 = c >> 7;
      int s = row96 / 48;
      int d = row96 - s * 48;
      int cb2 = c & 127;
      gload16(wbase + ((size_t)((2 * kp + s) * 48 + d)) * 128 + (cb2 ^ ((d & 7) << 4)),
              (char*)Wl + coff);
    }
    __syncthreads();
#pragma unroll
    for (int s = 0; s < 2; ++s) {
      int kk = 2 * kp + s;
#pragma unroll
      for (int cb = 0; cb < 2; ++cb) {
        bf16x8 a = *(const bf16x8*)((const char*)win + (w * 16 + c15 + kk) * 144 + cb * 64 + g4 * 16);
#pragma unroll
        for (int ct = 0; ct < 3; ++ct) {
          int d = ct * 16 + c15;
          bf16x8 bfrag = *(const bf16x8*)((const char*)Wl + s * 6144 + d * 128 +
                                          ((cb * 64 + g4 * 16) ^ ((d & 7) << 4)));
          acc[ct] = __builtin_amdgcn_mfma_f32_16x16x32_bf16(a, bfrag, acc[ct], 0, 0, 0);
        }
      }
    }
    __syncthreads();
  }

#pragma unroll
  for (int ct = 0; ct < 3; ++ct) {
    int dg = g * 48 + ct * 16 + c15;
    float bv = bias[dg];
#pragma unroll
    for (int r = 0; r < 4; ++r) {
      int l = l0 + w * 16 + g4 * 4 + r;
      size_t idx = (size_t)(b * 2048 + l) * 768 + dg;
      float vv = acc[ct][r] + bv;
      vv = 0.5f * vv * (1.0f + erff(vv * 0.70710678f));
      out[idx] = x[idx] + vv;
    }
  }
}

// ---------------------------------------------------------------- layernorm: wave-per-row, no barriers
__global__ __launch_bounds__(256) void ln_kernel(const float* __restrict__ a,
                                                 const float* __restrict__ r,
                                                 const float* __restrict__ g,
                                                 const float* __restrict__ be,
                                                 float* __restrict__ out,
                                                 bf16* __restrict__ outb) {
  int w = threadIdx.x >> 6, lane = threadIdx.x & 63;
  size_t row = (size_t)blockIdx.x * 4 + w;
  const float* ar = a + row * 768;
  const float* rr = r ? r + row * 768 : nullptr;
  float4 v[3];
  float s = 0.f;
#pragma unroll
  for (int i = 0; i < 3; ++i) {
    int c = lane * 4 + i * 256;
    float4 vv = *(const float4*)(ar + c);
    if (rr) {
      float4 rv = *(const float4*)(rr + c);
      vv.x += rv.x; vv.y += rv.y; vv.z += rv.z; vv.w += rv.w;
    }
    v[i] = vv;
    s += vv.x + vv.y + vv.z + vv.w;
  }
#pragma unroll
  for (int st = 1; st < 64; st <<= 1) s += __shfl_xor(s, st);
  float mean = s * (1.0f / 768.0f);
  float s2 = 0.f;
#pragma unroll
  for (int i = 0; i < 3; ++i) {
    float dx = v[i].x - mean, dy = v[i].y - mean, dz = v[i].z - mean, dw = v[i].w - mean;
    s2 += dx * dx + dy * dy + dz * dz + dw * dw;
  }
#pragma unroll
  for (int st = 1; st < 64; st <<= 1) s2 += __shfl_xor(s2, st);
  float rstd = rsqrtf(s2 * (1.0f / 768.0f) + 1e-5f);
#pragma unroll
  for (int i = 0; i < 3; ++i) {
    int c = lane * 4 + i * 256;
    float4 gv = *(const float4*)(g + c);
    float4 bv = *(const float4*)(be + c);
    float4 ov;
    ov.x = (v[i].x - mean) * rstd * gv.x + bv.x;
    ov.y = (v[i].y - mean) * rstd * gv.y + bv.y;
    ov.z = (v[i].z - mean) * rstd * gv.z + bv.z;
    ov.w = (v[i].w - mean) * rstd * gv.w + bv.w;
    *(float4*)(out + row * 768 + c) = ov;
    if (outb) {
      union { bf16 h[4]; uint2 u; } pk;
      pk.h[0] = __float2bfloat16(ov.x); pk.h[1] = __float2bfloat16(ov.y);
      pk.h[2] = __float2bfloat16(ov.z); pk.h[3] = __float2bfloat16(ov.w);
      *(uint2*)(outb + row * 768 + c) = pk.u;
    }
  }
}

// ---------------------------------------------------------------- transpose-cast f32 [R][C] -> bf16 [C][R]
__global__ __launch_bounds__(256) void castT_kernel(const float* __restrict__ src,
                                                    bf16* __restrict__ dst, int R, int C) {
  __shared__ float t[32][33];
  int c0 = blockIdx.x * 32, r0 = blockIdx.y * 32;
  int tx = threadIdx.x & 31, ty = threadIdx.x >> 5;
#pragma unroll
  for (int i = 0; i < 32; i += 8)
    t[ty + i][tx] = src[(size_t)(r0 + ty + i) * C + (c0 + tx)];
  __syncthreads();
#pragma unroll
  for (int i = 0; i < 32; i += 8)
    dst[(size_t)(c0 + ty + i) * R + (r0 + tx)] = __float2bfloat16(t[tx][ty + i]);
}

__global__ __launch_bounds__(256) void castT_qkv_kernel(const float* __restrict__ q,
                                                        const float* __restrict__ k,
                                                        const float* __restrict__ v,
                                                        bf16* __restrict__ dst) {
  int n0 = blockIdx.x * 32, k0 = blockIdx.y * 32;
  const float* src = (n0 < 768) ? q : (n0 < 1536) ? k : v;
  int nn = (n0 >= 1536) ? (n0 - 1536) : (n0 >= 768 ? n0 - 768 : n0);
  __shared__ float t[32][33];
  int tx = threadIdx.x & 31, ty = threadIdx.x >> 5;
#pragma unroll
  for (int i = 0; i < 32; i += 8)
    t[ty + i][tx] = src[(size_t)(k0 + ty + i) * 768 + nn + tx];
  __syncthreads();
#pragma unroll
  for (int i = 0; i < 32; i += 8)
    dst[(size_t)(n0 + ty + i) * 768 + k0 + tx] = __float2bfloat16(t[tx][ty + i]);
}

__global__ __launch_bounds__(256) void bcat_kernel(const float* __restrict__ bq,
                                                   const float* __restrict__ bk,
                                                   const float* __restrict__ bv,
                                                   float* __restrict__ dst) {
  int i = blockIdx.x * 256 + threadIdx.x;
  if (i >= 2304) return;
  dst[i] = (i < 768) ? bq[i] : (i < 1536) ? bk[i - 768] : bv[i - 1536];
}

// v slice of qkv [M][2304] -> vT [(b*12+h)*64 + d][2048]
__global__ __launch_bounds__(256) void vtrans_kernel(const bf16* __restrict__ qkv,
                                                     bf16* __restrict__ vT) {
  int l0 = blockIdx.x * 32, d0 = blockIdx.y * 32, bh = blockIdx.z;
  int b = bh / 12, h = bh % 12;
  __shared__ bf16 t[32][33];
  int tx = threadIdx.x & 31, ty = threadIdx.x >> 5;
#pragma unroll
  for (int i = 0; i < 32; i += 8)
    t[ty + i][tx] = qkv[(size_t)(b * 2048 + l0 + ty + i) * 2304 + 1536 + h * 64 + d0 + tx];
  __syncthreads();
#pragma unroll
  for (int i = 0; i < 32; i += 8)
    vT[((size_t)bh * 64 + d0 + ty + i) * 2048 + l0 + tx] = t[tx][ty + i];
}

// ---------------------------------------------------------------- bf16 MFMA GEMM (+XCD swizzle)
template <int BM, int BN, int GELU, int BF16OUT>
__global__ __launch_bounds__(256) void gemm_bf16(const bf16* __restrict__ A,
                                                 const bf16* __restrict__ BT,
                                                 const float* __restrict__ bias,
                                                 void* __restrict__ Cout,
                                                 int N, int Kd) {
  constexpr int WM = BM / 2, MF = WM / 16;
  constexpr int WN = BN / 2, FN = WN / 16;
  __shared__ bf16 As[BM * 64];
  __shared__ bf16 Bs[BN * 64];
  const int tid = threadIdx.x, w = tid >> 6, lane = tid & 63;
  int gx = gridDim.x;
  int flat = blockIdx.x + gx * blockIdx.y;
  int cpx = (gx * gridDim.y) >> 3;
  int sw = (flat & 7) * cpx + (flat >> 3);
  const int bn = sw % gx, bm = sw / gx;
  const int wr = w >> 1, wc = w & 1;
  const int c15 = lane & 15, g4 = lane >> 4;
  const int lrow8 = lane >> 3;
  const int cb = (lane & 7) * 16;

  f32x4 acc[MF][FN];
  const f32x4 vzero = {0.f, 0.f, 0.f, 0.f};
#pragma unroll
  for (int i = 0; i < MF; ++i)
#pragma unroll
    for (int j = 0; j < FN; ++j) acc[i][j] = vzero;

  const char* Ab = (const char*)A;
  const char* Bb = (const char*)BT;

  for (int k0 = 0; k0 < Kd; k0 += 64) {
#pragma unroll
    for (int i = 0; i < BM / 32; ++i) {
      int t = w + 4 * i;
      int row = t * 8 + lrow8;
      gload16(Ab + ((size_t)(bm * BM + row) * Kd + k0) * 2 + (cb ^ ((row & 7) << 4)),
              (char*)As + t * 1024);
    }
#pragma unroll
    for (int i = 0; i < BN / 32; ++i) {
      int t = w + 4 * i;
      int row = t * 8 + lrow8;
      gload16(Bb + ((size_t)(bn * BN + row) * Kd + k0) * 2 + (cb ^ ((row & 7) << 4)),
              (char*)Bs + t * 1024);
    }
    __syncthreads();
    bf16x8 af[MF][2], bfr[FN][2];
#pragma unroll
    for (int kf = 0; kf < 2; ++kf) {
      int kbyte = kf * 64 + g4 * 16;
#pragma unroll
      for (int mf = 0; mf < MF; ++mf) {
        int row = wr * WM + mf * 16 + c15;
        af[mf][kf] = *(const bf16x8*)((const char*)As + row * 128 + (kbyte ^ ((row & 7) << 4)));
      }
#pragma unroll
      for (int fn = 0; fn < FN; ++fn) {
        int row = wc * WN + fn * 16 + c15;
        bfr[fn][kf] = *(const bf16x8*)((const char*)Bs + row * 128 + (kbyte ^ ((row & 7) << 4)));
      }
    }
    __builtin_amdgcn_s_setprio(1);
#pragma unroll
    for (int mf = 0; mf < MF; ++mf)
#pragma unroll
      for (int fn = 0; fn < FN; ++fn) {
        acc[mf][fn] = __builtin_amdgcn_mfma_f32_16x16x32_bf16(af[mf][0], bfr[fn][0], acc[mf][fn], 0, 0, 0);
        acc[mf][fn] = __builtin_amdgcn_mfma_f32_16x16x32_bf16(af[mf][1], bfr[fn][1], acc[mf][fn], 0, 0, 0);
      }
    __builtin_amdgcn_s_setprio(0);
    __syncthreads();
  }
#pragma unroll
  for (int fn = 0; fn < FN; ++fn) {
    int col = bn * BN + wc * WN + fn * 16 + c15;
    float bv = bias[col];
#pragma unroll
    for (int mf = 0; mf < MF; ++mf) {
#pragma unroll
      for (int r = 0; r < 4; ++r) {
        int row = bm * BM + wr * WM + mf * 16 + g4 * 4 + r;
        float vv = acc[mf][fn][r] + bv;
        if (GELU) vv = 0.5f * vv * (1.0f + erff(vv * 0.70710678f));
        if (BF16OUT) ((bf16*)Cout)[(size_t)row * N + col] = __float2bfloat16(vv);
        else        ((float*)Cout)[(size_t)row * N + col] = vv;
      }
    }
  }
}

// ---------------------------------------------------------------- flash attention v4
// swapped QK^T (S^T via mfma(K,Q)) -> lane-local q-row softmax + packed b64 P writes
__global__ __launch_bounds__(256) void attn_mfma(const bf16* __restrict__ qkv,
                                                 const bf16* __restrict__ vT,
                                                 bf16* __restrict__ ob) {
  int bid = blockIdx.x + 32 * (blockIdx.y + 12 * blockIdx.z);
  int wgid = (bid & 7) * 96 + (bid >> 3);
  const int q0 = (wgid & 31) * 64;
  int bh = wgid >> 5;
  const int h = bh % 12, b = bh / 12;

  const int tid = threadIdx.x, w = tid >> 6, lane = tid & 63;
  const int c15 = lane & 15, g4 = lane >> 4;
  const int lrow8 = lane >> 3;
  const int cb = (lane & 7) * 16;
  __shared__ bf16 Kl[2][4096];
  __shared__ bf16 Vl[2][4096];
  __shared__ bf16 Pl[4096];

  const f32x4 vzero = {0.f, 0.f, 0.f, 0.f};
  const char* qp = (const char*)qkv + (((size_t)(b * 2048 + q0 + w * 16 + c15)) * 2304 + h * 64) * 2;
  bf16x8 qa0 = *(const bf16x8*)(qp + g4 * 16);
  bf16x8 qa1 = *(const bf16x8*)(qp + 64 + g4 * 16);

  bf16x8 b_one;
#pragma unroll
  for (int i = 0; i < 8; ++i) b_one[i] = (__bf16)1.0f;

  f32x4 o[4], o5;
#pragma unroll
  for (int i = 0; i < 4; ++i) o[i] = vzero;
  o5 = vzero;
  float m = -1e30f;                    // running max for q-row = c15 (exp2 domain)
  const float SC2 = 0.18033688f;       // SCALE_ * log2(e)
  const float THR = 11.54f;            // ~8 nats in exp2 domain

  const char* kgb = (const char*)qkv + (((size_t)(b * 2048)) * 2304 + 768 + h * 64) * 2;
  const char* vgb = (const char*)vT + ((size_t)((b * 12 + h) * 64) * 2048) * 2;
  char* Plw = (char*)Pl + w * 2048;

#define STAGE(kt, bufi)                                                                     \
  {                                                                                         \
    char* Kd = (char*)Kl[bufi];                                                             \
    char* Vd = (char*)Vl[bufi];                                                             \
    _Pragma("unroll")                                                                       \
    for (int i = 0; i < 2; ++i) {                                                           \
      int t = w + 4 * i;                                                                    \
      int rr = t * 8 + lrow8;                                                               \
      gload16(kgb + (size_t)((kt) * 64 + rr) * 4608 + (cb ^ ((rr & 7) << 4)), Kd + t * 1024);\
      gload16(vgb + (size_t)rr * 4096 + (size_t)(kt) * 128 + (cb ^ ((rr & 7) << 4)), Vd + t * 1024);\
    }                                                                                       \
  }

  STAGE(0, 0);
  __syncthreads();

  for (int kt = 0; kt < 32; ++kt) {
    int cur = kt & 1;
    if (kt + 1 < 32) STAGE(kt + 1, cur ^ 1);

    const char* Kc = (const char*)Kl[cur];
    const char* Vc = (const char*)Vl[cur];

    // S^T = K @ Q : sc[fn][r] = S[key = fn*16+g4*4+r][q = c15] (raw logits)
    f32x4 sc[4];
    __builtin_amdgcn_s_setprio(1);
#pragma unroll
    for (int fn = 0; fn < 4; ++fn) {
      int key = fn * 16 + c15;
      const char* kr = Kc + key * 128;
      int sw = (key & 7) << 4;
      bf16x8 kb0 = *(const bf16x8*)(kr + ((g4 * 16) ^ sw));
      bf16x8 kb1 = *(const bf16x8*)(kr + ((64 + g4 * 16) ^ sw));
      f32x4 s = __builtin_amdgcn_mfma_f32_16x16x32_bf16(kb0, qa0, vzero, 0, 0, 0);
      s = __builtin_amdgcn_mfma_f32_16x16x32_bf16(kb1, qa1, s, 0, 0, 0);
      sc[fn] = s;
    }
    __builtin_amdgcn_s_setprio(0);

    // lane-local max over this lane's 16 values (all belong to q-row c15)
    float pm = fmaxf(
        fmaxf(fmaxf(fmaxf(sc[0][0], sc[0][1]), fmaxf(sc[0][2], sc[0][3])),
              fmaxf(fmaxf(sc[1][0], sc[1][1]), fmaxf(sc[1][2], sc[1][3]))),
        fmaxf(fmaxf(fmaxf(sc[2][0], sc[2][1]), fmaxf(sc[2][2], sc[2][3])),
              fmaxf(fmaxf(sc[3][0], sc[3][1]), fmaxf(sc[3][2], sc[3][3]))));
    int ok = (pm * SC2 <= m + THR) ? 1 : 0;

    if (!__all(ok)) {
      // rescale path (rare): full row max across the 4 lane-groups sharing c15
      float tm = pm;
      tm = fmaxf(tm, __shfl_xor(tm, 16));
      tm = fmaxf(tm, __shfl_xor(tm, 32));
      float mn = fmaxf(m, tm * SC2);
      float alpha = exp2f(m - mn);
      m = mn;
      // redistribute alpha (indexed by q=c15) to accumulator rows (q = g4*4+r)
#pragma unroll
      for (int r = 0; r < 4; ++r) {
        float ar = __shfl(alpha, g4 * 4 + r);
        o[0][r] *= ar; o[1][r] *= ar; o[2][r] *= ar; o[3][r] *= ar;
        o5[r] *= ar;
      }
    }

    // P = exp2(S*SC2 - m), packed 4 consecutive keys -> one b64 LDS write
    {
      char* prow = Plw + c15 * 128;
      int swp = (c15 & 7) << 4;
#pragma unroll
      for (int fn = 0; fn < 4; ++fn) {
        union { bf16 hh[4]; uint2 u; } pk;
#pragma unroll
        for (int r = 0; r < 4; ++r)
          pk.hh[r] = __float2bfloat16(exp2f(fmaf(sc[fn][r], SC2, -m)));
        *(uint2*)(prow + ((fn * 32 + g4 * 8) ^ swp)) = pk.u;
      }
    }

    // PV: O += P @ V ; o5 += P @ 1
    {
      const char* pr = Plw + c15 * 128;
      int sw = (c15 & 7) << 4;
      bf16x8 pa0 = *(const bf16x8*)(pr + ((g4 * 16) ^ sw));
      bf16x8 pa1 = *(const bf16x8*)(pr + ((64 + g4 * 16) ^ sw));
      __builtin_amdgcn_s_setprio(1);
#pragma unroll
      for (int fh = 0; fh < 4; ++fh) {
        int hd = fh * 16 + c15;
        const char* vr = Vc + hd * 128;
        int swv = (hd & 7) << 4;
        bf16x8 vb0 = *(const bf16x8*)(vr + ((g4 * 16) ^ swv));
        bf16x8 vb1 = *(const bf16x8*)(vr + ((64 + g4 * 16) ^ swv));
        o[fh] = __builtin_amdgcn_mfma_f32_16x16x32_bf16(pa0, vb0, o[fh], 0, 0, 0);
        o[fh] = __builtin_amdgcn_mfma_f32_16x16x32_bf16(pa1, vb1, o[fh], 0, 0, 0);
      }
      o5 = __builtin_amdgcn_mfma_f32_16x16x32_bf16(pa0, b_one, o5, 0, 0, 0);
      o5 = __builtin_amdgcn_mfma_f32_16x16x32_bf16(pa1, b_one, o5, 0, 0, 0);
      __builtin_amdgcn_s_setprio(0);
    }
    __syncthreads();
  }
#undef STAGE

#pragma unroll
  for (int r = 0; r < 4; ++r) {
    float inv = 1.0f / o5[r];
    size_t row = (size_t)(b * 2048 + q0 + w * 16 + g4 * 4 + r);
#pragma unroll
    for (int fh = 0; fh < 4; ++fh)
      ob[row * 768 + h * 64 + fh * 16 + c15] = __float2bfloat16(o[fh][r] * inv);
  }
}

// ----------------------------------------------------------------
extern "C" void kernel_launch(void* const* d_in, const int* in_sizes, int n_in,
                              void* d_out, int out_size, void* d_ws, size_t ws_size,
                              hipStream_t stream) {
  const float* x      = (const float*)d_in[0];
  const float* pcw    = (const float*)d_in[1];
  const float* pcb    = (const float*)d_in[2];
  const float* ln0_g  = (const float*)d_in[3];
  const float* ln0_b  = (const float*)d_in[4];
  const float* Wq     = (const float*)d_in[5];
  const float* bq     = (const float*)d_in[6];
  const float* Wk     = (const float*)d_in[7];
  const float* bk     = (const float*)d_in[8];
  const float* Wv     = (const float*)d_in[9];
  const float* bv     = (const float*)d_in[10];
  const float* Wo     = (const float*)d_in[11];
  const float* bo     = (const float*)d_in[12];
  const float* ln1_g  = (const float*)d_in[13];
  const float* ln1_b  = (const float*)d_in[14];
  const float* W1     = (const float*)d_in[15];
  const float* b1     = (const float*)d_in[16];
  const float* W2     = (const float*)d_in[17];
  const float* b2     = (const float*)d_in[18];
  const float* ln2_g  = (const float*)d_in[19];
  const float* ln2_b  = (const float*)d_in[20];

  const size_t MDB = (size_t)M_TOK * D_ * 4;
  char* W = (char*)d_ws;
  float* h    = (float*)W;
  float* tmp  = (float*)(W + MDB);
  char*  big  = W + 2 * MDB;
  bf16*  qkv  = (bf16*)big;
  bf16*  ff   = (bf16*)big;
  bf16*  wT2  = (bf16*)big;
  char* p = W + 2 * MDB + 25165824;
  bf16* h_bf  = (bf16*)p; p += (size_t)M_TOK * D_ * 2;
  bf16* obuf  = (bf16*)p; p += (size_t)M_TOK * D_ * 2;
  bf16* vT    = (bf16*)p; p += (size_t)M_TOK * D_ * 2;
  bf16* wqkvb = (bf16*)p; p += (size_t)2304 * 768 * 2;
  bf16* wob   = (bf16*)p; p += (size_t)768 * 768 * 2;
  bf16* w1b   = (bf16*)p; p += (size_t)3072 * 768 * 2;
  bf16* w2b   = (bf16*)p; p += (size_t)768 * 3072 * 2;
  float* bqkv = (float*)p;

  convw_kernel<<<24576, 256, 0, stream>>>(pcw, wT2);
  conv_mfma<<<dim3(32, 16, 2), 256, 0, stream>>>(x, wT2, pcb, tmp);
  ln_kernel<<<M_TOK / 4, 256, 0, stream>>>(tmp, nullptr, ln0_g, ln0_b, h, h_bf);

  for (int l = 0; l < NL_; ++l) {
    const float* wq = Wq + (size_t)l * D_ * D_;
    const float* wk = Wk + (size_t)l * D_ * D_;
    const float* wv = Wv + (size_t)l * D_ * D_;
    const float* wo = Wo + (size_t)l * D_ * D_;
    const float* w1 = W1 + (size_t)l * D_ * F_;
    const float* w2 = W2 + (size_t)l * F_ * D_;

    castT_qkv_kernel<<<dim3(72, 24), 256, 0, stream>>>(wq, wk, wv, wqkvb);
    bcat_kernel<<<9, 256, 0, stream>>>(bq + (size_t)l * D_, bk + (size_t)l * D_, bv + (size_t)l * D_, bqkv);
    castT_kernel<<<dim3(24, 24), 256, 0, stream>>>(wo, wob, 768, 768);
    castT_kernel<<<dim3(96, 24), 256, 0, stream>>>(w1, w1b, 768, 3072);
    castT_kernel<<<dim3(24, 96), 256, 0, stream>>>(w2, w2b, 3072, 768);

    gemm_bf16<128, 128, 0, 1><<<dim3(18, 32), 256, 0, stream>>>(h_bf, wqkvb, bqkv, qkv, 2304, 768);
    vtrans_kernel<<<dim3(64, 2, 24), 256, 0, stream>>>(qkv, vT);
    attn_mfma<<<dim3(32, 12, 2), 256, 0, stream>>>(qkv, vT, obuf);
    gemm_bf16<64, 64, 0, 0><<<dim3(12, 64), 256, 0, stream>>>(obuf, wob, bo + (size_t)l * D_, tmp, 768, 768);
    ln_kernel<<<M_TOK / 4, 256, 0, stream>>>(tmp, h, ln1_g + (size_t)l * D_, ln1_b + (size_t)l * D_, h, h_bf);
    gemm_bf16<128, 128, 1, 1><<<dim3(24, 32), 256, 0, stream>>>(h_bf, w1b, b1 + (size_t)l * F_, ff, 3072, 768);
    gemm_bf16<64, 64, 0, 0><<<dim3(12, 64), 256, 0, stream>>>(ff, w2b, b2 + (size_t)l * D_, tmp, 768, 3072);
    float* out_ln2 = (l == NL_ - 1) ? (float*)d_out : h;
    ln_kernel<<<M_TOK / 4, 256, 0, stream>>>(tmp, h, ln2_g + (size_t)l * D_, ln2_b + (size_t)l * D_, out_ln2, h_bf);
  }
}